// Round 6
// baseline (433.763 us; speedup 1.0000x reference)
//
#include <hip/hip_runtime.h>

#define NN 100000
#define NE 1000000
#define D  64
#define CAP 32          // per-node bucket capacity; Poisson(10) ⇒ P(deg>32) ≈ 2e-9/node
#define OVF_CAP 16384
#define NBIN 782        // ceil(NN/128): bin = dst>>7
#define BINCAP 1536     // λ≈1280 edges/bin, +7σ; guarded anyway
#define NCH_LIN 1563    // ceil(NN/64)

// ======================= build pass 1: bin by dst>>7 =======================
__global__ void k_p1(const int* __restrict__ src, const int* __restrict__ dst,
                     int* __restrict__ bincnt, int* __restrict__ binbuf,
                     int* __restrict__ cnt_ovf, int* __restrict__ ovf_n,
                     int2* __restrict__ ovf) {
    int e = blockIdx.x * blockDim.x + threadIdx.x;
    if (e < NE) {
        int s = src[e], d = dst[e];
        int b = d >> 7;
        int c = atomicAdd(&bincnt[b], 1);
        if (c < BINCAP) {
            binbuf[b * BINCAP + c] = (s << 7) | (d & 127);   // src<2^17, packs in 24 bits
        } else {                                             // ~never
            int i = atomicAdd(ovf_n, 1);
            if (i < OVF_CAP) ovf[i] = make_int2(s, d);
            atomicAdd(&cnt_ovf[d], 1);                       // keep degree exact
        }
    }
}

// ======================= build pass 2: per-bin bucket fill + dinv =======================
__global__ __launch_bounds__(256) void k_p2(const int* __restrict__ bincnt,
                                            const int* __restrict__ binbuf,
                                            const int* __restrict__ cnt_ovf,
                                            int* __restrict__ cnt, float* __restrict__ dinv,
                                            int* __restrict__ bucket,
                                            int* __restrict__ ovf_n, int2* __restrict__ ovf) {
    __shared__ int lcnt[128];
    const int b = blockIdx.x;
    const int base = b * 128;
    const int nlocal = min(128, NN - base);
    int m = bincnt[b];
    if (m > BINCAP) m = BINCAP;
    for (int i = threadIdx.x; i < 128; i += 256) lcnt[i] = 0;
    __syncthreads();
    for (int e = threadIdx.x; e < m; e += 256) {
        int p = binbuf[b * BINCAP + e];
        int s = p >> 7, dl = p & 127;
        int c = atomicAdd(&lcnt[dl], 1);                     // LDS atomic: cheap
        if (c < CAP) {
            bucket[(size_t)(base + dl) * CAP + c] = s;       // 16 KB block-local region
        } else {                                             // rare node-cap overflow
            int i = atomicAdd(ovf_n, 1);
            if (i < OVF_CAP) ovf[i] = make_int2(s, base + dl);
        }
    }
    __syncthreads();
    for (int i = threadIdx.x; i < nlocal; i += 256) {
        int c = lcnt[i];
        cnt[base + i] = c;                                   // binned count (bucket iteration)
        dinv[base + i] = rsqrtf((float)(c + cnt_ovf[base + i] + 1));  // full degree + self loop
    }
}

// ======================= propagation (pull, 4 nodes/wave, float4) =======================
// out[n] = dinv[n] * ( dinv[n]*in[n] + sum_{s in N(n)} dinv[s]*in[s] )

__global__ __launch_bounds__(256) void k_gather32(const float4* __restrict__ in4,
                                                  const int* __restrict__ cnt,
                                                  const int* __restrict__ bucket,
                                                  const float* __restrict__ dinv,
                                                  float4* __restrict__ out4) {
    const int tid = threadIdx.x;
    const int l = tid & 15;
    const int n = blockIdx.x * 16 + (tid >> 4);   // 6250*16 == NN exactly

    const int deg = min(cnt[n], CAP);
    const float dn = dinv[n];

    float4 a0 = in4[(size_t)n * 16 + l];
    a0.x *= dn; a0.y *= dn; a0.z *= dn; a0.w *= dn;
    float4 a1 = make_float4(0.f, 0.f, 0.f, 0.f);
    float4 a2 = make_float4(0.f, 0.f, 0.f, 0.f);
    float4 a3 = make_float4(0.f, 0.f, 0.f, 0.f);

    if (deg > 0) {
        int   iA = (l < deg) ? l : 0;
        int   sA = bucket[n * CAP + iA];
        float wA = dinv[sA];
        const int kmax = deg < 16 ? deg : 16;
        int k = 0;
        for (; k + 3 < kmax; k += 4) {
            int   s0 = __shfl(sA, k + 0, 16);
            int   s1 = __shfl(sA, k + 1, 16);
            int   s2 = __shfl(sA, k + 2, 16);
            int   s3 = __shfl(sA, k + 3, 16);
            float w0 = __shfl(wA, k + 0, 16);
            float w1 = __shfl(wA, k + 1, 16);
            float w2 = __shfl(wA, k + 2, 16);
            float w3 = __shfl(wA, k + 3, 16);
            float4 r0 = in4[(size_t)s0 * 16 + l];
            float4 r1 = in4[(size_t)s1 * 16 + l];
            float4 r2 = in4[(size_t)s2 * 16 + l];
            float4 r3 = in4[(size_t)s3 * 16 + l];
            a0.x = fmaf(w0, r0.x, a0.x); a0.y = fmaf(w0, r0.y, a0.y);
            a0.z = fmaf(w0, r0.z, a0.z); a0.w = fmaf(w0, r0.w, a0.w);
            a1.x = fmaf(w1, r1.x, a1.x); a1.y = fmaf(w1, r1.y, a1.y);
            a1.z = fmaf(w1, r1.z, a1.z); a1.w = fmaf(w1, r1.w, a1.w);
            a2.x = fmaf(w2, r2.x, a2.x); a2.y = fmaf(w2, r2.y, a2.y);
            a2.z = fmaf(w2, r2.z, a2.z); a2.w = fmaf(w2, r2.w, a2.w);
            a3.x = fmaf(w3, r3.x, a3.x); a3.y = fmaf(w3, r3.y, a3.y);
            a3.z = fmaf(w3, r3.z, a3.z); a3.w = fmaf(w3, r3.w, a3.w);
        }
        for (; k < kmax; ++k) {
            int   s0 = __shfl(sA, k, 16);
            float w0 = __shfl(wA, k, 16);
            float4 r0 = in4[(size_t)s0 * 16 + l];
            a0.x = fmaf(w0, r0.x, a0.x); a0.y = fmaf(w0, r0.y, a0.y);
            a0.z = fmaf(w0, r0.z, a0.z); a0.w = fmaf(w0, r0.w, a0.w);
        }
        if (deg > 16) {   // ~3% of nodes
            int   iB = (16 + l < deg) ? (16 + l) : 0;
            int   sB = bucket[n * CAP + iB];
            float wB = dinv[sB];
            const int k2max = deg - 16;
            int k2 = 0;
            for (; k2 + 1 < k2max; k2 += 2) {
                int   s0 = __shfl(sB, k2 + 0, 16);
                int   s1 = __shfl(sB, k2 + 1, 16);
                float w0 = __shfl(wB, k2 + 0, 16);
                float w1 = __shfl(wB, k2 + 1, 16);
                float4 r0 = in4[(size_t)s0 * 16 + l];
                float4 r1 = in4[(size_t)s1 * 16 + l];
                a1.x = fmaf(w0, r0.x, a1.x); a1.y = fmaf(w0, r0.y, a1.y);
                a1.z = fmaf(w0, r0.z, a1.z); a1.w = fmaf(w0, r0.w, a1.w);
                a2.x = fmaf(w1, r1.x, a2.x); a2.y = fmaf(w1, r1.y, a2.y);
                a2.z = fmaf(w1, r1.z, a2.z); a2.w = fmaf(w1, r1.w, a2.w);
            }
            if (k2 < k2max) {
                int   s0 = __shfl(sB, k2, 16);
                float w0 = __shfl(wB, k2, 16);
                float4 r0 = in4[(size_t)s0 * 16 + l];
                a3.x = fmaf(w0, r0.x, a3.x); a3.y = fmaf(w0, r0.y, a3.y);
                a3.z = fmaf(w0, r0.z, a3.z); a3.w = fmaf(w0, r0.w, a3.w);
            }
        }
    }
    float4 r;
    r.x = dn * ((a0.x + a1.x) + (a2.x + a3.x));
    r.y = dn * ((a0.y + a1.y) + (a2.y + a3.y));
    r.z = dn * ((a0.z + a1.z) + (a2.z + a3.z));
    r.w = dn * ((a0.w + a1.w) + (a2.w + a3.w));
    out4[(size_t)n * 16 + l] = r;
}

// overflow fixup: out[dst] += dinv[dst]*dinv[src]*in[src]  (normally 0 entries)
__global__ void k_ovf(const float4* __restrict__ in4, const int* __restrict__ ovf_n,
                      const int2* __restrict__ ovf, const float* __restrict__ dinv,
                      float* __restrict__ out) {
    int m = *ovf_n;
    if (m > OVF_CAP) m = OVF_CAP;
    int total = m * 16;
    for (int idx = blockIdx.x * blockDim.x + threadIdx.x; idx < total;
         idx += gridDim.x * blockDim.x) {
        int e = idx >> 4, l = idx & 15;
        int2 p = ovf[e];
        float w = dinv[p.x] * dinv[p.y];
        float4 r = in4[(size_t)p.x * 16 + l];
        float* o = &out[(size_t)p.y * D + 4 * l];
        atomicAdd(o + 0, w * r.x);
        atomicAdd(o + 1, w * r.y);
        atomicAdd(o + 2, w * r.z);
        atomicAdd(o + 3, w * r.w);
    }
}

// ======================= linear (in-place safe: row-local) =======================
__global__ __launch_bounds__(256) void k_linear4(const float4* in4,
                                                 const float* __restrict__ W,
                                                 const float* __restrict__ bias,
                                                 float4* out4) {
    __shared__ float4 Wq[64 * 16];     // Wq[i*16+l] = {W[4l+c][i], c=0..3}
    __shared__ float rowbuf[64][68];

    const int tid = threadIdx.x;
    for (int m = tid; m < 64 * 16; m += 256) {
        int i = m >> 4, l = m & 15;
        float4 v;
        v.x = W[(4 * l + 0) * 64 + i];
        v.y = W[(4 * l + 1) * 64 + i];
        v.z = W[(4 * l + 2) * 64 + i];
        v.w = W[(4 * l + 3) * 64 + i];
        Wq[m] = v;
    }
    __syncthreads();

    const int g = tid >> 4;
    const int l = tid & 15;
    const float4 bv = *(const float4*)&bias[4 * l];

    for (int chunk = blockIdx.x; chunk < NCH_LIN; chunk += gridDim.x) {
        const int nb = chunk * 64 + 4 * g;
        const int n0 = nb, n1 = nb + 1, n2 = nb + 2, n3 = nb + 3;
        float4 r0 = in4[(size_t)(n0 < NN ? n0 : NN - 1) * 16 + l];
        float4 r1 = in4[(size_t)(n1 < NN ? n1 : NN - 1) * 16 + l];
        float4 r2 = in4[(size_t)(n2 < NN ? n2 : NN - 1) * 16 + l];
        float4 r3 = in4[(size_t)(n3 < NN ? n3 : NN - 1) * 16 + l];
        *(float4*)&rowbuf[4 * g + 0][4 * l] = r0;
        *(float4*)&rowbuf[4 * g + 1][4 * l] = r1;
        *(float4*)&rowbuf[4 * g + 2][4 * l] = r2;
        *(float4*)&rowbuf[4 * g + 3][4 * l] = r3;

        float4 y0 = bv, y1 = bv, y2 = bv, y3 = bv;
        #pragma unroll
        for (int kq = 0; kq < 16; ++kq) {
            float4 ri0 = *(const float4*)&rowbuf[4 * g + 0][4 * kq];
            float4 ri1 = *(const float4*)&rowbuf[4 * g + 1][4 * kq];
            float4 ri2 = *(const float4*)&rowbuf[4 * g + 2][4 * kq];
            float4 ri3 = *(const float4*)&rowbuf[4 * g + 3][4 * kq];
            float4 wq0 = Wq[(4 * kq + 0) * 16 + l];
            float4 wq1 = Wq[(4 * kq + 1) * 16 + l];
            float4 wq2 = Wq[(4 * kq + 2) * 16 + l];
            float4 wq3 = Wq[(4 * kq + 3) * 16 + l];
            y0.x = fmaf(ri0.x, wq0.x, y0.x); y0.y = fmaf(ri0.x, wq0.y, y0.y);
            y0.z = fmaf(ri0.x, wq0.z, y0.z); y0.w = fmaf(ri0.x, wq0.w, y0.w);
            y0.x = fmaf(ri0.y, wq1.x, y0.x); y0.y = fmaf(ri0.y, wq1.y, y0.y);
            y0.z = fmaf(ri0.y, wq1.z, y0.z); y0.w = fmaf(ri0.y, wq1.w, y0.w);
            y0.x = fmaf(ri0.z, wq2.x, y0.x); y0.y = fmaf(ri0.z, wq2.y, y0.y);
            y0.z = fmaf(ri0.z, wq2.z, y0.z); y0.w = fmaf(ri0.z, wq2.w, y0.w);
            y0.x = fmaf(ri0.w, wq3.x, y0.x); y0.y = fmaf(ri0.w, wq3.y, y0.y);
            y0.z = fmaf(ri0.w, wq3.z, y0.z); y0.w = fmaf(ri0.w, wq3.w, y0.w);

            y1.x = fmaf(ri1.x, wq0.x, y1.x); y1.y = fmaf(ri1.x, wq0.y, y1.y);
            y1.z = fmaf(ri1.x, wq0.z, y1.z); y1.w = fmaf(ri1.x, wq0.w, y1.w);
            y1.x = fmaf(ri1.y, wq1.x, y1.x); y1.y = fmaf(ri1.y, wq1.y, y1.y);
            y1.z = fmaf(ri1.y, wq1.z, y1.z); y1.w = fmaf(ri1.y, wq1.w, y1.w);
            y1.x = fmaf(ri1.z, wq2.x, y1.x); y1.y = fmaf(ri1.z, wq2.y, y1.y);
            y1.z = fmaf(ri1.z, wq2.z, y1.z); y1.w = fmaf(ri1.z, wq2.w, y1.w);
            y1.x = fmaf(ri1.w, wq3.x, y1.x); y1.y = fmaf(ri1.w, wq3.y, y1.y);
            y1.z = fmaf(ri1.w, wq3.z, y1.z); y1.w = fmaf(ri1.w, wq3.w, y1.w);

            y2.x = fmaf(ri2.x, wq0.x, y2.x); y2.y = fmaf(ri2.x, wq0.y, y2.y);
            y2.z = fmaf(ri2.x, wq0.z, y2.z); y2.w = fmaf(ri2.x, wq0.w, y2.w);
            y2.x = fmaf(ri2.y, wq1.x, y2.x); y2.y = fmaf(ri2.y, wq1.y, y2.y);
            y2.z = fmaf(ri2.y, wq1.z, y2.z); y2.w = fmaf(ri2.y, wq1.w, y2.w);
            y2.x = fmaf(ri2.z, wq2.x, y2.x); y2.y = fmaf(ri2.z, wq2.y, y2.y);
            y2.z = fmaf(ri2.z, wq2.z, y2.z); y2.w = fmaf(ri2.z, wq2.w, y2.w);
            y2.x = fmaf(ri2.w, wq3.x, y2.x); y2.y = fmaf(ri2.w, wq3.y, y2.y);
            y2.z = fmaf(ri2.w, wq3.z, y2.z); y2.w = fmaf(ri2.w, wq3.w, y2.w);

            y3.x = fmaf(ri3.x, wq0.x, y3.x); y3.y = fmaf(ri3.x, wq0.y, y3.y);
            y3.z = fmaf(ri3.x, wq0.z, y3.z); y3.w = fmaf(ri3.x, wq0.w, y3.w);
            y3.x = fmaf(ri3.y, wq1.x, y3.x); y3.y = fmaf(ri3.y, wq1.y, y3.y);
            y3.z = fmaf(ri3.y, wq1.z, y3.z); y3.w = fmaf(ri3.y, wq1.w, y3.w);
            y3.x = fmaf(ri3.z, wq2.x, y3.x); y3.y = fmaf(ri3.z, wq2.y, y3.y);
            y3.z = fmaf(ri3.z, wq2.z, y3.z); y3.w = fmaf(ri3.z, wq2.w, y3.w);
            y3.x = fmaf(ri3.w, wq3.x, y3.x); y3.y = fmaf(ri3.w, wq3.y, y3.y);
            y3.z = fmaf(ri3.w, wq3.z, y3.z); y3.w = fmaf(ri3.w, wq3.w, y3.w);
        }
        if (n0 < NN) out4[(size_t)n0 * 16 + l] = y0;
        if (n1 < NN) out4[(size_t)n1 * 16 + l] = y1;
        if (n2 < NN) out4[(size_t)n2 * 16 + l] = y2;
        if (n3 < NN) out4[(size_t)n3 * 16 + l] = y3;
    }
}

// ======================= fallback path (atomic scatter, round-1) =======================

__global__ void k_init_deg(float* __restrict__ deg) {
    int n = blockIdx.x * blockDim.x + threadIdx.x;
    if (n < NN) deg[n] = 1.0f;
}
__global__ void k_count_deg(const int* __restrict__ dst, float* __restrict__ deg) {
    int e = blockIdx.x * blockDim.x + threadIdx.x;
    if (e < NE) atomicAdd(&deg[dst[e]], 1.0f);
}
__global__ void k_dinv_f(float* __restrict__ deg) {
    int n = blockIdx.x * blockDim.x + threadIdx.x;
    if (n < NN) deg[n] = rsqrtf(deg[n]);
}
__global__ void k_prop_init(const float* __restrict__ in, const float* __restrict__ dinv,
                            float* __restrict__ out) {
    int i = blockIdx.x * blockDim.x + threadIdx.x;
    if (i < NN * D) {
        int n = i >> 6;
        float di = dinv[n];
        out[i] = di * di * in[i];
    }
}
__global__ __launch_bounds__(256) void k_prop_edges(const float* __restrict__ in,
                                                    const int* __restrict__ src,
                                                    const int* __restrict__ dst,
                                                    const float* __restrict__ dinv,
                                                    float* __restrict__ out) {
    int t = blockIdx.x * blockDim.x + threadIdx.x;
    int e = t >> 6, f = t & 63;
    if (e < NE) {
        int s = src[e], d = dst[e];
        float w = dinv[s] * dinv[d];
        atomicAdd(&out[d * D + f], w * in[s * D + f]);
    }
}
__global__ __launch_bounds__(256) void k_linear(const float* __restrict__ in,
                                                const float* __restrict__ W,
                                                const float* __restrict__ bias,
                                                float* __restrict__ out) {
    __shared__ float Wt[64 * 65];
    __shared__ float rows[4][64];
    const int tid = threadIdx.x;
    for (int m = tid; m < 64 * 64; m += 256) {
        int o = m >> 6, i = m & 63;
        Wt[i * 65 + o] = W[m];
    }
    __syncthreads();
    const int wave = tid >> 6, lane = tid & 63;
    const float bo = bias[lane];
    for (int base = blockIdx.x * 4; base < NN; base += gridDim.x * 4) {
        int n = base + wave;
        if (n < NN) {
            rows[wave][lane] = in[n * D + lane];
            float acc = bo;
            #pragma unroll
            for (int i = 0; i < 64; ++i)
                acc = fmaf(rows[wave][i], Wt[i * 65 + lane], acc);
            out[n * D + lane] = acc;
        }
    }
}

// ======================= launch =======================

extern "C" void kernel_launch(void* const* d_in, const int* in_sizes, int n_in,
                              void* d_out, int out_size, void* d_ws, size_t ws_size,
                              hipStream_t stream) {
    const float* x   = (const float*)d_in[0];
    const int*   ei  = (const int*)d_in[1];
    const float* W   = (const float*)d_in[2];
    const float* b   = (const float*)d_in[3];
    float* out = (float*)d_out;

    const int* src = ei;        // edge_index[0]
    const int* dst = ei + NE;   // edge_index[1]

    char* ws = (char*)d_ws;
    size_t off = 0;
    auto take = [&](size_t bytes) -> char* {
        char* p = ws + off;
        off = (off + bytes + 255) & ~(size_t)255;
        return p;
    };

    int*   cnt     = (int*)take((size_t)NN * 4);
    float* dinv    = (float*)take((size_t)NN * 4);
    int*   cnt_ovf = (int*)take((size_t)NN * 4);
    int*   bincnt  = (int*)take((size_t)NBIN * 4);
    int*   ovf_n   = (int*)take(256);
    int2*  ovf     = (int2*)take((size_t)OVF_CAP * 8);
    float* buf     = (float*)take((size_t)NN * D * 4);
    int*   binbuf  = (int*)buf;   // aliases buf: binbuf dead before hop2 writes buf
    int*   bucket  = (int*)take((size_t)NN * CAP * 4);
    const bool use_bucket = (off <= ws_size);

    const int B = 256;
    const int gridE1 = (NE + B - 1) / B;   // 3907
    const int gridN1 = (NN + B - 1) / B;   // 391
    const int gridNW = NN / 16;            // 6250

    if (use_bucket) {
        hipMemsetAsync(bincnt, 0, (size_t)NBIN * 4, stream);
        hipMemsetAsync(cnt_ovf, 0, (size_t)NN * 4, stream);
        hipMemsetAsync(ovf_n, 0, 4, stream);
        k_p1<<<gridE1, B, 0, stream>>>(src, dst, bincnt, binbuf, cnt_ovf, ovf_n, ovf);
        k_p2<<<NBIN, B, 0, stream>>>(bincnt, binbuf, cnt_ovf, cnt, dinv, bucket, ovf_n, ovf);

        const float4* x4   = (const float4*)x;
        float4*       out4 = (float4*)out;
        float4*       buf4 = (float4*)buf;
        // hop1: x -> out
        k_gather32<<<gridNW, B, 0, stream>>>(x4, cnt, bucket, dinv, out4);
        k_ovf<<<32, B, 0, stream>>>(x4, ovf_n, ovf, dinv, (float*)out4);
        // hop2: out -> buf   (binbuf dead from here on)
        k_gather32<<<gridNW, B, 0, stream>>>((const float4*)out4, cnt, bucket, dinv, buf4);
        k_ovf<<<32, B, 0, stream>>>((const float4*)out4, ovf_n, ovf, dinv, (float*)buf4);
        // hop3: buf -> out
        k_gather32<<<gridNW, B, 0, stream>>>((const float4*)buf4, cnt, bucket, dinv, out4);
        k_ovf<<<32, B, 0, stream>>>((const float4*)buf4, ovf_n, ovf, dinv, (float*)out4);
        // linear in-place
        k_linear4<<<1024, B, 0, stream>>>((const float4*)out4, W, b, out4);
    } else {
        const int gridF = (NN * D + B - 1) / B;
        const int gridEW = (NE * 64) / B;
        k_init_deg <<<gridN1, B, 0, stream>>>(dinv);
        k_count_deg<<<gridE1, B, 0, stream>>>(dst, dinv);
        k_dinv_f   <<<gridN1, B, 0, stream>>>(dinv);
        k_prop_init <<<gridF, B, 0, stream>>>(x, dinv, buf);
        k_prop_edges<<<gridEW, B, 0, stream>>>(x, src, dst, dinv, buf);
        k_prop_init <<<gridF, B, 0, stream>>>(buf, dinv, out);
        k_prop_edges<<<gridEW, B, 0, stream>>>(buf, src, dst, dinv, out);
        k_prop_init <<<gridF, B, 0, stream>>>(out, dinv, buf);
        k_prop_edges<<<gridEW, B, 0, stream>>>(out, src, dst, dinv, buf);
        k_linear<<<NN / 4, B, 0, stream>>>(buf, W, b, out);
    }
}

// Round 7
// 433.165 us; speedup vs baseline: 1.0014x; 1.0014x over previous
//
#include <hip/hip_runtime.h>

#define NN 100000
#define NE 1000000
#define D  64
#define CAP 32          // per-node bucket capacity; Poisson(10) ⇒ P(deg>32) ≈ 2e-9/node
#define OVF_CAP 16384
#define NBIN 782        // ceil(NN/128): bin = dst>>7
#define BINCAP 1536     // λ≈1280 edges/bin, +7σ; guarded anyway
#define NCH_LIN 1563    // ceil(NN/64)

// ======================= build pass 1: bin by dst>>7 =======================
__global__ void k_p1(const int* __restrict__ src, const int* __restrict__ dst,
                     int* __restrict__ bincnt, int* __restrict__ binbuf,
                     int* __restrict__ cnt_ovf, int* __restrict__ ovf_n,
                     int2* __restrict__ ovf) {
    int e = blockIdx.x * blockDim.x + threadIdx.x;
    if (e < NE) {
        int s = src[e], d = dst[e];
        int b = d >> 7;
        int c = atomicAdd(&bincnt[b], 1);
        if (c < BINCAP) {
            binbuf[b * BINCAP + c] = (s << 7) | (d & 127);   // src<2^17, packs in 24 bits
        } else {                                             // ~never
            int i = atomicAdd(ovf_n, 1);
            if (i < OVF_CAP) ovf[i] = make_int2(s, d);
            atomicAdd(&cnt_ovf[d], 1);                       // keep degree exact
        }
    }
}

// ======================= build pass 2: per-bin bucket fill + dinv =======================
__global__ __launch_bounds__(256) void k_p2(const int* __restrict__ bincnt,
                                            const int* __restrict__ binbuf,
                                            const int* __restrict__ cnt_ovf,
                                            int* __restrict__ cnt, float* __restrict__ dinv,
                                            int* __restrict__ bucket,
                                            int* __restrict__ ovf_n, int2* __restrict__ ovf) {
    __shared__ int lcnt[128];
    const int b = blockIdx.x;
    const int base = b * 128;
    const int nlocal = min(128, NN - base);
    int m = bincnt[b];
    if (m > BINCAP) m = BINCAP;
    for (int i = threadIdx.x; i < 128; i += 256) lcnt[i] = 0;
    __syncthreads();
    for (int e = threadIdx.x; e < m; e += 256) {
        int p = binbuf[b * BINCAP + e];
        int s = p >> 7, dl = p & 127;
        int c = atomicAdd(&lcnt[dl], 1);                     // LDS atomic: cheap
        if (c < CAP) {
            bucket[(size_t)(base + dl) * CAP + c] = s;       // 16 KB block-local region
        } else {                                             // rare node-cap overflow
            int i = atomicAdd(ovf_n, 1);
            if (i < OVF_CAP) ovf[i] = make_int2(s, base + dl);
        }
    }
    __syncthreads();
    for (int i = threadIdx.x; i < nlocal; i += 256) {
        int c = lcnt[i];
        cnt[base + i] = c;                                   // binned count (bucket iteration)
        dinv[base + i] = rsqrtf((float)(c + cnt_ovf[base + i] + 1));  // full degree + self loop
    }
}

// ======================= propagation (pull, 4 nodes/wave, float4) =======================
// out[n] = dinv[n] * ( dinv[n]*in[n] + sum_{s in N(n)} dinv[s]*in[s] )

__global__ __launch_bounds__(256) void k_gather32(const float4* __restrict__ in4,
                                                  const int* __restrict__ cnt,
                                                  const int* __restrict__ bucket,
                                                  const float* __restrict__ dinv,
                                                  float4* __restrict__ out4) {
    const int tid = threadIdx.x;
    const int l = tid & 15;
    const int n = blockIdx.x * 16 + (tid >> 4);   // 6250*16 == NN exactly

    const int deg = min(cnt[n], CAP);
    const float dn = dinv[n];

    float4 a0 = in4[(size_t)n * 16 + l];
    a0.x *= dn; a0.y *= dn; a0.z *= dn; a0.w *= dn;
    float4 a1 = make_float4(0.f, 0.f, 0.f, 0.f);
    float4 a2 = make_float4(0.f, 0.f, 0.f, 0.f);
    float4 a3 = make_float4(0.f, 0.f, 0.f, 0.f);

    if (deg > 0) {
        int   iA = (l < deg) ? l : 0;
        int   sA = bucket[n * CAP + iA];
        float wA = dinv[sA];
        const int kmax = deg < 16 ? deg : 16;
        int k = 0;
        for (; k + 3 < kmax; k += 4) {
            int   s0 = __shfl(sA, k + 0, 16);
            int   s1 = __shfl(sA, k + 1, 16);
            int   s2 = __shfl(sA, k + 2, 16);
            int   s3 = __shfl(sA, k + 3, 16);
            float w0 = __shfl(wA, k + 0, 16);
            float w1 = __shfl(wA, k + 1, 16);
            float w2 = __shfl(wA, k + 2, 16);
            float w3 = __shfl(wA, k + 3, 16);
            float4 r0 = in4[(size_t)s0 * 16 + l];
            float4 r1 = in4[(size_t)s1 * 16 + l];
            float4 r2 = in4[(size_t)s2 * 16 + l];
            float4 r3 = in4[(size_t)s3 * 16 + l];
            a0.x = fmaf(w0, r0.x, a0.x); a0.y = fmaf(w0, r0.y, a0.y);
            a0.z = fmaf(w0, r0.z, a0.z); a0.w = fmaf(w0, r0.w, a0.w);
            a1.x = fmaf(w1, r1.x, a1.x); a1.y = fmaf(w1, r1.y, a1.y);
            a1.z = fmaf(w1, r1.z, a1.z); a1.w = fmaf(w1, r1.w, a1.w);
            a2.x = fmaf(w2, r2.x, a2.x); a2.y = fmaf(w2, r2.y, a2.y);
            a2.z = fmaf(w2, r2.z, a2.z); a2.w = fmaf(w2, r2.w, a2.w);
            a3.x = fmaf(w3, r3.x, a3.x); a3.y = fmaf(w3, r3.y, a3.y);
            a3.z = fmaf(w3, r3.z, a3.z); a3.w = fmaf(w3, r3.w, a3.w);
        }
        for (; k < kmax; ++k) {
            int   s0 = __shfl(sA, k, 16);
            float w0 = __shfl(wA, k, 16);
            float4 r0 = in4[(size_t)s0 * 16 + l];
            a0.x = fmaf(w0, r0.x, a0.x); a0.y = fmaf(w0, r0.y, a0.y);
            a0.z = fmaf(w0, r0.z, a0.z); a0.w = fmaf(w0, r0.w, a0.w);
        }
        if (deg > 16) {   // ~3% of nodes
            int   iB = (16 + l < deg) ? (16 + l) : 0;
            int   sB = bucket[n * CAP + iB];
            float wB = dinv[sB];
            const int k2max = deg - 16;
            int k2 = 0;
            for (; k2 + 1 < k2max; k2 += 2) {
                int   s0 = __shfl(sB, k2 + 0, 16);
                int   s1 = __shfl(sB, k2 + 1, 16);
                float w0 = __shfl(wB, k2 + 0, 16);
                float w1 = __shfl(wB, k2 + 1, 16);
                float4 r0 = in4[(size_t)s0 * 16 + l];
                float4 r1 = in4[(size_t)s1 * 16 + l];
                a1.x = fmaf(w0, r0.x, a1.x); a1.y = fmaf(w0, r0.y, a1.y);
                a1.z = fmaf(w0, r0.z, a1.z); a1.w = fmaf(w0, r0.w, a1.w);
                a2.x = fmaf(w1, r1.x, a2.x); a2.y = fmaf(w1, r1.y, a2.y);
                a2.z = fmaf(w1, r1.z, a2.z); a2.w = fmaf(w1, r1.w, a2.w);
            }
            if (k2 < k2max) {
                int   s0 = __shfl(sB, k2, 16);
                float w0 = __shfl(wB, k2, 16);
                float4 r0 = in4[(size_t)s0 * 16 + l];
                a3.x = fmaf(w0, r0.x, a3.x); a3.y = fmaf(w0, r0.y, a3.y);
                a3.z = fmaf(w0, r0.z, a3.z); a3.w = fmaf(w0, r0.w, a3.w);
            }
        }
    }
    float4 r;
    r.x = dn * ((a0.x + a1.x) + (a2.x + a3.x));
    r.y = dn * ((a0.y + a1.y) + (a2.y + a3.y));
    r.z = dn * ((a0.z + a1.z) + (a2.z + a3.z));
    r.w = dn * ((a0.w + a1.w) + (a2.w + a3.w));
    out4[(size_t)n * 16 + l] = r;
}

// overflow fixup: out[dst] += dinv[dst]*dinv[src]*in[src]  (normally 0 entries)
__global__ void k_ovf(const float4* __restrict__ in4, const int* __restrict__ ovf_n,
                      const int2* __restrict__ ovf, const float* __restrict__ dinv,
                      float* __restrict__ out) {
    int m = *ovf_n;
    if (m > OVF_CAP) m = OVF_CAP;
    int total = m * 16;
    for (int idx = blockIdx.x * blockDim.x + threadIdx.x; idx < total;
         idx += gridDim.x * blockDim.x) {
        int e = idx >> 4, l = idx & 15;
        int2 p = ovf[e];
        float w = dinv[p.x] * dinv[p.y];
        float4 r = in4[(size_t)p.x * 16 + l];
        float* o = &out[(size_t)p.y * D + 4 * l];
        atomicAdd(o + 0, w * r.x);
        atomicAdd(o + 1, w * r.y);
        atomicAdd(o + 2, w * r.z);
        atomicAdd(o + 3, w * r.w);
    }
}

// ======================= linear (in-place safe: row-local) =======================
__global__ __launch_bounds__(256) void k_linear4(const float4* in4,
                                                 const float* __restrict__ W,
                                                 const float* __restrict__ bias,
                                                 float4* out4) {
    __shared__ float4 Wq[64 * 16];     // Wq[i*16+l] = {W[4l+c][i], c=0..3}
    __shared__ float rowbuf[64][68];

    const int tid = threadIdx.x;
    for (int m = tid; m < 64 * 16; m += 256) {
        int i = m >> 4, l = m & 15;
        float4 v;
        v.x = W[(4 * l + 0) * 64 + i];
        v.y = W[(4 * l + 1) * 64 + i];
        v.z = W[(4 * l + 2) * 64 + i];
        v.w = W[(4 * l + 3) * 64 + i];
        Wq[m] = v;
    }
    __syncthreads();

    const int g = tid >> 4;
    const int l = tid & 15;
    const float4 bv = *(const float4*)&bias[4 * l];

    for (int chunk = blockIdx.x; chunk < NCH_LIN; chunk += gridDim.x) {
        const int nb = chunk * 64 + 4 * g;
        const int n0 = nb, n1 = nb + 1, n2 = nb + 2, n3 = nb + 3;
        float4 r0 = in4[(size_t)(n0 < NN ? n0 : NN - 1) * 16 + l];
        float4 r1 = in4[(size_t)(n1 < NN ? n1 : NN - 1) * 16 + l];
        float4 r2 = in4[(size_t)(n2 < NN ? n2 : NN - 1) * 16 + l];
        float4 r3 = in4[(size_t)(n3 < NN ? n3 : NN - 1) * 16 + l];
        *(float4*)&rowbuf[4 * g + 0][4 * l] = r0;
        *(float4*)&rowbuf[4 * g + 1][4 * l] = r1;
        *(float4*)&rowbuf[4 * g + 2][4 * l] = r2;
        *(float4*)&rowbuf[4 * g + 3][4 * l] = r3;

        float4 y0 = bv, y1 = bv, y2 = bv, y3 = bv;
        #pragma unroll
        for (int kq = 0; kq < 16; ++kq) {
            float4 ri0 = *(const float4*)&rowbuf[4 * g + 0][4 * kq];
            float4 ri1 = *(const float4*)&rowbuf[4 * g + 1][4 * kq];
            float4 ri2 = *(const float4*)&rowbuf[4 * g + 2][4 * kq];
            float4 ri3 = *(const float4*)&rowbuf[4 * g + 3][4 * kq];
            float4 wq0 = Wq[(4 * kq + 0) * 16 + l];
            float4 wq1 = Wq[(4 * kq + 1) * 16 + l];
            float4 wq2 = Wq[(4 * kq + 2) * 16 + l];
            float4 wq3 = Wq[(4 * kq + 3) * 16 + l];
            y0.x = fmaf(ri0.x, wq0.x, y0.x); y0.y = fmaf(ri0.x, wq0.y, y0.y);
            y0.z = fmaf(ri0.x, wq0.z, y0.z); y0.w = fmaf(ri0.x, wq0.w, y0.w);
            y0.x = fmaf(ri0.y, wq1.x, y0.x); y0.y = fmaf(ri0.y, wq1.y, y0.y);
            y0.z = fmaf(ri0.y, wq1.z, y0.z); y0.w = fmaf(ri0.y, wq1.w, y0.w);
            y0.x = fmaf(ri0.z, wq2.x, y0.x); y0.y = fmaf(ri0.z, wq2.y, y0.y);
            y0.z = fmaf(ri0.z, wq2.z, y0.z); y0.w = fmaf(ri0.z, wq2.w, y0.w);
            y0.x = fmaf(ri0.w, wq3.x, y0.x); y0.y = fmaf(ri0.w, wq3.y, y0.y);
            y0.z = fmaf(ri0.w, wq3.z, y0.z); y0.w = fmaf(ri0.w, wq3.w, y0.w);

            y1.x = fmaf(ri1.x, wq0.x, y1.x); y1.y = fmaf(ri1.x, wq0.y, y1.y);
            y1.z = fmaf(ri1.x, wq0.z, y1.z); y1.w = fmaf(ri1.x, wq0.w, y1.w);
            y1.x = fmaf(ri1.y, wq1.x, y1.x); y1.y = fmaf(ri1.y, wq1.y, y1.y);
            y1.z = fmaf(ri1.y, wq1.z, y1.z); y1.w = fmaf(ri1.y, wq1.w, y1.w);
            y1.x = fmaf(ri1.z, wq2.x, y1.x); y1.y = fmaf(ri1.z, wq2.y, y1.y);
            y1.z = fmaf(ri1.z, wq2.z, y1.z); y1.w = fmaf(ri1.z, wq2.w, y1.w);
            y1.x = fmaf(ri1.w, wq3.x, y1.x); y1.y = fmaf(ri1.w, wq3.y, y1.y);
            y1.z = fmaf(ri1.w, wq3.z, y1.z); y1.w = fmaf(ri1.w, wq3.w, y1.w);

            y2.x = fmaf(ri2.x, wq0.x, y2.x); y2.y = fmaf(ri2.x, wq0.y, y2.y);
            y2.z = fmaf(ri2.x, wq0.z, y2.z); y2.w = fmaf(ri2.x, wq0.w, y2.w);
            y2.x = fmaf(ri2.y, wq1.x, y2.x); y2.y = fmaf(ri2.y, wq1.y, y2.y);
            y2.z = fmaf(ri2.y, wq1.z, y2.z); y2.w = fmaf(ri2.y, wq1.w, y2.w);
            y2.x = fmaf(ri2.z, wq2.x, y2.x); y2.y = fmaf(ri2.z, wq2.y, y2.y);
            y2.z = fmaf(ri2.z, wq2.z, y2.z); y2.w = fmaf(ri2.z, wq2.w, y2.w);
            y2.x = fmaf(ri2.w, wq3.x, y2.x); y2.y = fmaf(ri2.w, wq3.y, y2.y);
            y2.z = fmaf(ri2.w, wq3.z, y2.z); y2.w = fmaf(ri2.w, wq3.w, y2.w);

            y3.x = fmaf(ri3.x, wq0.x, y3.x); y3.y = fmaf(ri3.x, wq0.y, y3.y);
            y3.z = fmaf(ri3.x, wq0.z, y3.z); y3.w = fmaf(ri3.x, wq0.w, y3.w);
            y3.x = fmaf(ri3.y, wq1.x, y3.x); y3.y = fmaf(ri3.y, wq1.y, y3.y);
            y3.z = fmaf(ri3.y, wq1.z, y3.z); y3.w = fmaf(ri3.y, wq1.w, y3.w);
            y3.x = fmaf(ri3.z, wq2.x, y3.x); y3.y = fmaf(ri3.z, wq2.y, y3.y);
            y3.z = fmaf(ri3.z, wq2.z, y3.z); y3.w = fmaf(ri3.z, wq2.w, y3.w);
            y3.x = fmaf(ri3.w, wq3.x, y3.x); y3.y = fmaf(ri3.w, wq3.y, y3.y);
            y3.z = fmaf(ri3.w, wq3.z, y3.z); y3.w = fmaf(ri3.w, wq3.w, y3.w);
        }
        if (n0 < NN) out4[(size_t)n0 * 16 + l] = y0;
        if (n1 < NN) out4[(size_t)n1 * 16 + l] = y1;
        if (n2 < NN) out4[(size_t)n2 * 16 + l] = y2;
        if (n3 < NN) out4[(size_t)n3 * 16 + l] = y3;
    }
}

// ======================= fallback path (atomic scatter, round-1) =======================

__global__ void k_init_deg(float* __restrict__ deg) {
    int n = blockIdx.x * blockDim.x + threadIdx.x;
    if (n < NN) deg[n] = 1.0f;
}
__global__ void k_count_deg(const int* __restrict__ dst, float* __restrict__ deg) {
    int e = blockIdx.x * blockDim.x + threadIdx.x;
    if (e < NE) atomicAdd(&deg[dst[e]], 1.0f);
}
__global__ void k_dinv_f(float* __restrict__ deg) {
    int n = blockIdx.x * blockDim.x + threadIdx.x;
    if (n < NN) deg[n] = rsqrtf(deg[n]);
}
__global__ void k_prop_init(const float* __restrict__ in, const float* __restrict__ dinv,
                            float* __restrict__ out) {
    int i = blockIdx.x * blockDim.x + threadIdx.x;
    if (i < NN * D) {
        int n = i >> 6;
        float di = dinv[n];
        out[i] = di * di * in[i];
    }
}
__global__ __launch_bounds__(256) void k_prop_edges(const float* __restrict__ in,
                                                    const int* __restrict__ src,
                                                    const int* __restrict__ dst,
                                                    const float* __restrict__ dinv,
                                                    float* __restrict__ out) {
    int t = blockIdx.x * blockDim.x + threadIdx.x;
    int e = t >> 6, f = t & 63;
    if (e < NE) {
        int s = src[e], d = dst[e];
        float w = dinv[s] * dinv[d];
        atomicAdd(&out[d * D + f], w * in[s * D + f]);
    }
}
__global__ __launch_bounds__(256) void k_linear(const float* __restrict__ in,
                                                const float* __restrict__ W,
                                                const float* __restrict__ bias,
                                                float* __restrict__ out) {
    __shared__ float Wt[64 * 65];
    __shared__ float rows[4][64];
    const int tid = threadIdx.x;
    for (int m = tid; m < 64 * 64; m += 256) {
        int o = m >> 6, i = m & 63;
        Wt[i * 65 + o] = W[m];
    }
    __syncthreads();
    const int wave = tid >> 6, lane = tid & 63;
    const float bo = bias[lane];
    for (int base = blockIdx.x * 4; base < NN; base += gridDim.x * 4) {
        int n = base + wave;
        if (n < NN) {
            rows[wave][lane] = in[n * D + lane];
            float acc = bo;
            #pragma unroll
            for (int i = 0; i < 64; ++i)
                acc = fmaf(rows[wave][i], Wt[i * 65 + lane], acc);
            out[n * D + lane] = acc;
        }
    }
}

// ======================= launch =======================

extern "C" void kernel_launch(void* const* d_in, const int* in_sizes, int n_in,
                              void* d_out, int out_size, void* d_ws, size_t ws_size,
                              hipStream_t stream) {
    const float* x   = (const float*)d_in[0];
    const int*   ei  = (const int*)d_in[1];
    const float* W   = (const float*)d_in[2];
    const float* b   = (const float*)d_in[3];
    float* out = (float*)d_out;

    const int* src = ei;        // edge_index[0]
    const int* dst = ei + NE;   // edge_index[1]

    char* ws = (char*)d_ws;
    size_t off = 0;
    auto take = [&](size_t bytes) -> char* {
        char* p = ws + off;
        off = (off + bytes + 255) & ~(size_t)255;
        return p;
    };

    int*   cnt     = (int*)take((size_t)NN * 4);
    float* dinv    = (float*)take((size_t)NN * 4);
    int*   cnt_ovf = (int*)take((size_t)NN * 4);
    int*   bincnt  = (int*)take((size_t)NBIN * 4);
    int*   ovf_n   = (int*)take(256);
    int2*  ovf     = (int2*)take((size_t)OVF_CAP * 8);
    float* buf     = (float*)take((size_t)NN * D * 4);
    int*   binbuf  = (int*)buf;   // aliases buf: binbuf dead before hop2 writes buf
    int*   bucket  = (int*)take((size_t)NN * CAP * 4);
    const bool use_bucket = (off <= ws_size);

    const int B = 256;
    const int gridE1 = (NE + B - 1) / B;   // 3907
    const int gridN1 = (NN + B - 1) / B;   // 391
    const int gridNW = NN / 16;            // 6250

    if (use_bucket) {
        hipMemsetAsync(bincnt, 0, (size_t)NBIN * 4, stream);
        hipMemsetAsync(cnt_ovf, 0, (size_t)NN * 4, stream);
        hipMemsetAsync(ovf_n, 0, 4, stream);
        k_p1<<<gridE1, B, 0, stream>>>(src, dst, bincnt, binbuf, cnt_ovf, ovf_n, ovf);
        k_p2<<<NBIN, B, 0, stream>>>(bincnt, binbuf, cnt_ovf, cnt, dinv, bucket, ovf_n, ovf);

        const float4* x4   = (const float4*)x;
        float4*       out4 = (float4*)out;
        float4*       buf4 = (float4*)buf;
        // hop1: x -> out
        k_gather32<<<gridNW, B, 0, stream>>>(x4, cnt, bucket, dinv, out4);
        k_ovf<<<32, B, 0, stream>>>(x4, ovf_n, ovf, dinv, (float*)out4);
        // hop2: out -> buf   (binbuf dead from here on)
        k_gather32<<<gridNW, B, 0, stream>>>((const float4*)out4, cnt, bucket, dinv, buf4);
        k_ovf<<<32, B, 0, stream>>>((const float4*)out4, ovf_n, ovf, dinv, (float*)buf4);
        // hop3: buf -> out
        k_gather32<<<gridNW, B, 0, stream>>>((const float4*)buf4, cnt, bucket, dinv, out4);
        k_ovf<<<32, B, 0, stream>>>((const float4*)buf4, ovf_n, ovf, dinv, (float*)out4);
        // linear in-place
        k_linear4<<<1024, B, 0, stream>>>((const float4*)out4, W, b, out4);
    } else {
        const int gridF = (NN * D + B - 1) / B;
        const int gridEW = (NE * 64) / B;
        k_init_deg <<<gridN1, B, 0, stream>>>(dinv);
        k_count_deg<<<gridE1, B, 0, stream>>>(dst, dinv);
        k_dinv_f   <<<gridN1, B, 0, stream>>>(dinv);
        k_prop_init <<<gridF, B, 0, stream>>>(x, dinv, buf);
        k_prop_edges<<<gridEW, B, 0, stream>>>(x, src, dst, dinv, buf);
        k_prop_init <<<gridF, B, 0, stream>>>(buf, dinv, out);
        k_prop_edges<<<gridEW, B, 0, stream>>>(buf, src, dst, dinv, out);
        k_prop_init <<<gridF, B, 0, stream>>>(out, dinv, buf);
        k_prop_edges<<<gridEW, B, 0, stream>>>(out, src, dst, dinv, buf);
        k_linear<<<NN / 4, B, 0, stream>>>(buf, W, b, out);
    }
}

// Round 8
// 226.635 us; speedup vs baseline: 1.9139x; 1.9113x over previous
//
#include <hip/hip_runtime.h>

#define NN 100000
#define NE 1000000
#define D  64
#define CAP 32          // per-node bucket capacity; Poisson(10) ⇒ P(deg>32) ≈ 2e-9/node
#define OVF_CAP 16384
#define NCH_LIN 1563    // ceil(NN/64)

#define FILL_EPT 8                                        // edges per thread
#define FILL_CHUNK (256 * FILL_EPT)                       // 2048
#define FILL_NCHUNK ((NE + FILL_CHUNK - 1) / FILL_CHUNK)  // 489
#define PART_SZ 12500                                     // NN/8

// ======================= bucket build: XCD-partitioned writes =======================
// Block b: edge chunk b>>3, dst-partition b&7. The 8 sibling blocks share the
// chunk's lines via L2/IC; each bucket line is written from one XCD only
// (blockIdx%8 -> XCD round-robin), so partial lines merge once, not 8 times.
__global__ __launch_bounds__(256) void k_fill_bucket(const int* __restrict__ src,
                                                     const int* __restrict__ dst,
                                                     int* __restrict__ cnt,
                                                     int* __restrict__ bucket,
                                                     int* __restrict__ ovf_n,
                                                     int2* __restrict__ ovf) {
    const int part = blockIdx.x & 7;
    const int lo = part * PART_SZ, hi = lo + PART_SZ;
    const int base = (blockIdx.x >> 3) * FILL_CHUNK + threadIdx.x;
    #pragma unroll
    for (int it = 0; it < FILL_EPT; ++it) {
        int e = base + it * 256;
        if (e < NE) {
            int d = dst[e];
            if (d >= lo && d < hi) {
                int s = src[e];
                int c = atomicAdd(&cnt[d], 1);
                if (c < CAP) {
                    bucket[(size_t)d * CAP + c] = s;
                } else {                                 // ~never
                    int i = atomicAdd(ovf_n, 1);
                    if (i < OVF_CAP) ovf[i] = make_int2(s, d);
                }
            }
        }
    }
}

__global__ void k_dinv(const int* __restrict__ cnt, float* __restrict__ dinv) {
    int n = blockIdx.x * blockDim.x + threadIdx.x;
    if (n < NN) dinv[n] = rsqrtf((float)(cnt[n] + 1));   // +1 self loop
}

// ======================= propagation (pull, 4 nodes/wave, float4) =======================
// out[n] = dinv[n] * ( dinv[n]*in[n] + sum_{s in N(n)} dinv[s]*in[s] )
// Overflow edges (ovf_n ~always 0) handled inline: lanes scan the tiny list.

__global__ __launch_bounds__(256) void k_gather32(const float4* __restrict__ in4,
                                                  const int* __restrict__ cnt,
                                                  const int* __restrict__ bucket,
                                                  const float* __restrict__ dinv,
                                                  const int* __restrict__ ovf_n,
                                                  const int2* __restrict__ ovf,
                                                  float4* __restrict__ out4) {
    const int tid = threadIdx.x;
    const int l = tid & 15;
    const int n = blockIdx.x * 16 + (tid >> 4);   // 6250*16 == NN exactly

    const int deg = min(cnt[n], CAP);
    const float dn = dinv[n];

    float4 a0 = in4[(size_t)n * 16 + l];
    a0.x *= dn; a0.y *= dn; a0.z *= dn; a0.w *= dn;
    float4 a1 = make_float4(0.f, 0.f, 0.f, 0.f);
    float4 a2 = make_float4(0.f, 0.f, 0.f, 0.f);
    float4 a3 = make_float4(0.f, 0.f, 0.f, 0.f);

    if (deg > 0) {
        int   iA = (l < deg) ? l : 0;
        int   sA = bucket[n * CAP + iA];
        float wA = dinv[sA];
        const int kmax = deg < 16 ? deg : 16;
        int k = 0;
        for (; k + 3 < kmax; k += 4) {
            int   s0 = __shfl(sA, k + 0, 16);
            int   s1 = __shfl(sA, k + 1, 16);
            int   s2 = __shfl(sA, k + 2, 16);
            int   s3 = __shfl(sA, k + 3, 16);
            float w0 = __shfl(wA, k + 0, 16);
            float w1 = __shfl(wA, k + 1, 16);
            float w2 = __shfl(wA, k + 2, 16);
            float w3 = __shfl(wA, k + 3, 16);
            float4 r0 = in4[(size_t)s0 * 16 + l];
            float4 r1 = in4[(size_t)s1 * 16 + l];
            float4 r2 = in4[(size_t)s2 * 16 + l];
            float4 r3 = in4[(size_t)s3 * 16 + l];
            a0.x = fmaf(w0, r0.x, a0.x); a0.y = fmaf(w0, r0.y, a0.y);
            a0.z = fmaf(w0, r0.z, a0.z); a0.w = fmaf(w0, r0.w, a0.w);
            a1.x = fmaf(w1, r1.x, a1.x); a1.y = fmaf(w1, r1.y, a1.y);
            a1.z = fmaf(w1, r1.z, a1.z); a1.w = fmaf(w1, r1.w, a1.w);
            a2.x = fmaf(w2, r2.x, a2.x); a2.y = fmaf(w2, r2.y, a2.y);
            a2.z = fmaf(w2, r2.z, a2.z); a2.w = fmaf(w2, r2.w, a2.w);
            a3.x = fmaf(w3, r3.x, a3.x); a3.y = fmaf(w3, r3.y, a3.y);
            a3.z = fmaf(w3, r3.z, a3.z); a3.w = fmaf(w3, r3.w, a3.w);
        }
        for (; k < kmax; ++k) {
            int   s0 = __shfl(sA, k, 16);
            float w0 = __shfl(wA, k, 16);
            float4 r0 = in4[(size_t)s0 * 16 + l];
            a0.x = fmaf(w0, r0.x, a0.x); a0.y = fmaf(w0, r0.y, a0.y);
            a0.z = fmaf(w0, r0.z, a0.z); a0.w = fmaf(w0, r0.w, a0.w);
        }
        if (deg > 16) {   // ~3% of nodes
            int   iB = (16 + l < deg) ? (16 + l) : 0;
            int   sB = bucket[n * CAP + iB];
            float wB = dinv[sB];
            const int k2max = deg - 16;
            int k2 = 0;
            for (; k2 + 1 < k2max; k2 += 2) {
                int   s0 = __shfl(sB, k2 + 0, 16);
                int   s1 = __shfl(sB, k2 + 1, 16);
                float w0 = __shfl(wB, k2 + 0, 16);
                float w1 = __shfl(wB, k2 + 1, 16);
                float4 r0 = in4[(size_t)s0 * 16 + l];
                float4 r1 = in4[(size_t)s1 * 16 + l];
                a1.x = fmaf(w0, r0.x, a1.x); a1.y = fmaf(w0, r0.y, a1.y);
                a1.z = fmaf(w0, r0.z, a1.z); a1.w = fmaf(w0, r0.w, a1.w);
                a2.x = fmaf(w1, r1.x, a2.x); a2.y = fmaf(w1, r1.y, a2.y);
                a2.z = fmaf(w1, r1.z, a2.z); a2.w = fmaf(w1, r1.w, a2.w);
            }
            if (k2 < k2max) {
                int   s0 = __shfl(sB, k2, 16);
                float w0 = __shfl(wB, k2, 16);
                float4 r0 = in4[(size_t)s0 * 16 + l];
                a3.x = fmaf(w0, r0.x, a3.x); a3.y = fmaf(w0, r0.y, a3.y);
                a3.z = fmaf(w0, r0.z, a3.z); a3.w = fmaf(w0, r0.w, a3.w);
            }
        }
    }

    // inline overflow fixup (ovf_n is ~always 0; one hot scalar load)
    int m = *ovf_n;
    if (m > 0) {
        if (m > OVF_CAP) m = OVF_CAP;
        for (int i = 0; i < m; ++i) {
            int2 p = ovf[i];
            if (p.y == n) {
                float w = dinv[p.x];
                float4 r = in4[(size_t)p.x * 16 + l];
                a0.x = fmaf(w, r.x, a0.x); a0.y = fmaf(w, r.y, a0.y);
                a0.z = fmaf(w, r.z, a0.z); a0.w = fmaf(w, r.w, a0.w);
            }
        }
    }

    float4 r;
    r.x = dn * ((a0.x + a1.x) + (a2.x + a3.x));
    r.y = dn * ((a0.y + a1.y) + (a2.y + a3.y));
    r.z = dn * ((a0.z + a1.z) + (a2.z + a3.z));
    r.w = dn * ((a0.w + a1.w) + (a2.w + a3.w));
    out4[(size_t)n * 16 + l] = r;
}

// ======================= linear (in-place safe: row-local) =======================
__global__ __launch_bounds__(256) void k_linear4(const float4* in4,
                                                 const float* __restrict__ W,
                                                 const float* __restrict__ bias,
                                                 float4* out4) {
    __shared__ float4 Wq[64 * 16];     // Wq[i*16+l] = {W[4l+c][i], c=0..3}
    __shared__ float rowbuf[64][68];

    const int tid = threadIdx.x;
    for (int m = tid; m < 64 * 16; m += 256) {
        int i = m >> 4, l = m & 15;
        float4 v;
        v.x = W[(4 * l + 0) * 64 + i];
        v.y = W[(4 * l + 1) * 64 + i];
        v.z = W[(4 * l + 2) * 64 + i];
        v.w = W[(4 * l + 3) * 64 + i];
        Wq[m] = v;
    }
    __syncthreads();

    const int g = tid >> 4;
    const int l = tid & 15;
    const float4 bv = *(const float4*)&bias[4 * l];

    for (int chunk = blockIdx.x; chunk < NCH_LIN; chunk += gridDim.x) {
        const int nb = chunk * 64 + 4 * g;
        const int n0 = nb, n1 = nb + 1, n2 = nb + 2, n3 = nb + 3;
        float4 r0 = in4[(size_t)(n0 < NN ? n0 : NN - 1) * 16 + l];
        float4 r1 = in4[(size_t)(n1 < NN ? n1 : NN - 1) * 16 + l];
        float4 r2 = in4[(size_t)(n2 < NN ? n2 : NN - 1) * 16 + l];
        float4 r3 = in4[(size_t)(n3 < NN ? n3 : NN - 1) * 16 + l];
        *(float4*)&rowbuf[4 * g + 0][4 * l] = r0;
        *(float4*)&rowbuf[4 * g + 1][4 * l] = r1;
        *(float4*)&rowbuf[4 * g + 2][4 * l] = r2;
        *(float4*)&rowbuf[4 * g + 3][4 * l] = r3;

        float4 y0 = bv, y1 = bv, y2 = bv, y3 = bv;
        #pragma unroll
        for (int kq = 0; kq < 16; ++kq) {
            float4 ri0 = *(const float4*)&rowbuf[4 * g + 0][4 * kq];
            float4 ri1 = *(const float4*)&rowbuf[4 * g + 1][4 * kq];
            float4 ri2 = *(const float4*)&rowbuf[4 * g + 2][4 * kq];
            float4 ri3 = *(const float4*)&rowbuf[4 * g + 3][4 * kq];
            float4 wq0 = Wq[(4 * kq + 0) * 16 + l];
            float4 wq1 = Wq[(4 * kq + 1) * 16 + l];
            float4 wq2 = Wq[(4 * kq + 2) * 16 + l];
            float4 wq3 = Wq[(4 * kq + 3) * 16 + l];
            y0.x = fmaf(ri0.x, wq0.x, y0.x); y0.y = fmaf(ri0.x, wq0.y, y0.y);
            y0.z = fmaf(ri0.x, wq0.z, y0.z); y0.w = fmaf(ri0.x, wq0.w, y0.w);
            y0.x = fmaf(ri0.y, wq1.x, y0.x); y0.y = fmaf(ri0.y, wq1.y, y0.y);
            y0.z = fmaf(ri0.y, wq1.z, y0.z); y0.w = fmaf(ri0.y, wq1.w, y0.w);
            y0.x = fmaf(ri0.z, wq2.x, y0.x); y0.y = fmaf(ri0.z, wq2.y, y0.y);
            y0.z = fmaf(ri0.z, wq2.z, y0.z); y0.w = fmaf(ri0.z, wq2.w, y0.w);
            y0.x = fmaf(ri0.w, wq3.x, y0.x); y0.y = fmaf(ri0.w, wq3.y, y0.y);
            y0.z = fmaf(ri0.w, wq3.z, y0.z); y0.w = fmaf(ri0.w, wq3.w, y0.w);

            y1.x = fmaf(ri1.x, wq0.x, y1.x); y1.y = fmaf(ri1.x, wq0.y, y1.y);
            y1.z = fmaf(ri1.x, wq0.z, y1.z); y1.w = fmaf(ri1.x, wq0.w, y1.w);
            y1.x = fmaf(ri1.y, wq1.x, y1.x); y1.y = fmaf(ri1.y, wq1.y, y1.y);
            y1.z = fmaf(ri1.y, wq1.z, y1.z); y1.w = fmaf(ri1.y, wq1.w, y1.w);
            y1.x = fmaf(ri1.z, wq2.x, y1.x); y1.y = fmaf(ri1.z, wq2.y, y1.y);
            y1.z = fmaf(ri1.z, wq2.z, y1.z); y1.w = fmaf(ri1.z, wq2.w, y1.w);
            y1.x = fmaf(ri1.w, wq3.x, y1.x); y1.y = fmaf(ri1.w, wq3.y, y1.y);
            y1.z = fmaf(ri1.w, wq3.z, y1.z); y1.w = fmaf(ri1.w, wq3.w, y1.w);

            y2.x = fmaf(ri2.x, wq0.x, y2.x); y2.y = fmaf(ri2.x, wq0.y, y2.y);
            y2.z = fmaf(ri2.x, wq0.z, y2.z); y2.w = fmaf(ri2.x, wq0.w, y2.w);
            y2.x = fmaf(ri2.y, wq1.x, y2.x); y2.y = fmaf(ri2.y, wq1.y, y2.y);
            y2.z = fmaf(ri2.y, wq1.z, y2.z); y2.w = fmaf(ri2.y, wq1.w, y2.w);
            y2.x = fmaf(ri2.z, wq2.x, y2.x); y2.y = fmaf(ri2.z, wq2.y, y2.y);
            y2.z = fmaf(ri2.z, wq2.z, y2.z); y2.w = fmaf(ri2.z, wq2.w, y2.w);
            y2.x = fmaf(ri2.w, wq3.x, y2.x); y2.y = fmaf(ri2.w, wq3.y, y2.y);
            y2.z = fmaf(ri2.w, wq3.z, y2.z); y2.w = fmaf(ri2.w, wq3.w, y2.w);

            y3.x = fmaf(ri3.x, wq0.x, y3.x); y3.y = fmaf(ri3.x, wq0.y, y3.y);
            y3.z = fmaf(ri3.x, wq0.z, y3.z); y3.w = fmaf(ri3.x, wq0.w, y3.w);
            y3.x = fmaf(ri3.y, wq1.x, y3.x); y3.y = fmaf(ri3.y, wq1.y, y3.y);
            y3.z = fmaf(ri3.y, wq1.z, y3.z); y3.w = fmaf(ri3.y, wq1.w, y3.w);
            y3.x = fmaf(ri3.z, wq2.x, y3.x); y3.y = fmaf(ri3.z, wq2.y, y3.y);
            y3.z = fmaf(ri3.z, wq2.z, y3.z); y3.w = fmaf(ri3.z, wq2.w, y3.w);
            y3.x = fmaf(ri3.w, wq3.x, y3.x); y3.y = fmaf(ri3.w, wq3.y, y3.y);
            y3.z = fmaf(ri3.w, wq3.z, y3.z); y3.w = fmaf(ri3.w, wq3.w, y3.w);
        }
        if (n0 < NN) out4[(size_t)n0 * 16 + l] = y0;
        if (n1 < NN) out4[(size_t)n1 * 16 + l] = y1;
        if (n2 < NN) out4[(size_t)n2 * 16 + l] = y2;
        if (n3 < NN) out4[(size_t)n3 * 16 + l] = y3;
    }
}

// ======================= fallback path (atomic scatter, round-1) =======================

__global__ void k_init_deg(float* __restrict__ deg) {
    int n = blockIdx.x * blockDim.x + threadIdx.x;
    if (n < NN) deg[n] = 1.0f;
}
__global__ void k_count_deg(const int* __restrict__ dst, float* __restrict__ deg) {
    int e = blockIdx.x * blockDim.x + threadIdx.x;
    if (e < NE) atomicAdd(&deg[dst[e]], 1.0f);
}
__global__ void k_dinv_f(float* __restrict__ deg) {
    int n = blockIdx.x * blockDim.x + threadIdx.x;
    if (n < NN) deg[n] = rsqrtf(deg[n]);
}
__global__ void k_prop_init(const float* __restrict__ in, const float* __restrict__ dinv,
                            float* __restrict__ out) {
    int i = blockIdx.x * blockDim.x + threadIdx.x;
    if (i < NN * D) {
        int n = i >> 6;
        float di = dinv[n];
        out[i] = di * di * in[i];
    }
}
__global__ __launch_bounds__(256) void k_prop_edges(const float* __restrict__ in,
                                                    const int* __restrict__ src,
                                                    const int* __restrict__ dst,
                                                    const float* __restrict__ dinv,
                                                    float* __restrict__ out) {
    int t = blockIdx.x * blockDim.x + threadIdx.x;
    int e = t >> 6, f = t & 63;
    if (e < NE) {
        int s = src[e], d = dst[e];
        float w = dinv[s] * dinv[d];
        atomicAdd(&out[d * D + f], w * in[s * D + f]);
    }
}
__global__ __launch_bounds__(256) void k_linear(const float* __restrict__ in,
                                                const float* __restrict__ W,
                                                const float* __restrict__ bias,
                                                float* __restrict__ out) {
    __shared__ float Wt[64 * 65];
    __shared__ float rows[4][64];
    const int tid = threadIdx.x;
    for (int m = tid; m < 64 * 64; m += 256) {
        int o = m >> 6, i = m & 63;
        Wt[i * 65 + o] = W[m];
    }
    __syncthreads();
    const int wave = tid >> 6, lane = tid & 63;
    const float bo = bias[lane];
    for (int base = blockIdx.x * 4; base < NN; base += gridDim.x * 4) {
        int n = base + wave;
        if (n < NN) {
            rows[wave][lane] = in[n * D + lane];
            float acc = bo;
            #pragma unroll
            for (int i = 0; i < 64; ++i)
                acc = fmaf(rows[wave][i], Wt[i * 65 + lane], acc);
            out[n * D + lane] = acc;
        }
    }
}

// ======================= launch =======================

extern "C" void kernel_launch(void* const* d_in, const int* in_sizes, int n_in,
                              void* d_out, int out_size, void* d_ws, size_t ws_size,
                              hipStream_t stream) {
    const float* x   = (const float*)d_in[0];
    const int*   ei  = (const int*)d_in[1];
    const float* W   = (const float*)d_in[2];
    const float* b   = (const float*)d_in[3];
    float* out = (float*)d_out;

    const int* src = ei;        // edge_index[0]
    const int* dst = ei + NE;   // edge_index[1]

    char* ws = (char*)d_ws;
    size_t off = 0;
    auto take = [&](size_t bytes) -> char* {
        char* p = ws + off;
        off = (off + bytes + 255) & ~(size_t)255;
        return p;
    };

    int*   cnt    = (int*)take((size_t)NN * 4);
    float* dinv   = (float*)take((size_t)NN * 4);
    int*   ovf_n  = (int*)take(256);
    int2*  ovf    = (int2*)take((size_t)OVF_CAP * 8);
    float* buf    = (float*)take((size_t)NN * D * 4);
    int*   bucket = (int*)take((size_t)NN * CAP * 4);
    const bool use_bucket = (off <= ws_size);

    const int B = 256;
    const int gridE1 = (NE + B - 1) / B;   // 3907
    const int gridN1 = (NN + B - 1) / B;   // 391
    const int gridNW = NN / 16;            // 6250

    if (use_bucket) {
        hipMemsetAsync(cnt, 0, (size_t)NN * 4, stream);
        hipMemsetAsync(ovf_n, 0, 4, stream);
        k_fill_bucket<<<FILL_NCHUNK * 8, B, 0, stream>>>(src, dst, cnt, bucket, ovf_n, ovf);
        k_dinv<<<gridN1, B, 0, stream>>>(cnt, dinv);

        const float4* x4   = (const float4*)x;
        float4*       out4 = (float4*)out;
        float4*       buf4 = (float4*)buf;
        // hop1: x -> out
        k_gather32<<<gridNW, B, 0, stream>>>(x4, cnt, bucket, dinv, ovf_n, ovf, out4);
        // hop2: out -> buf
        k_gather32<<<gridNW, B, 0, stream>>>((const float4*)out4, cnt, bucket, dinv, ovf_n, ovf, buf4);
        // hop3: buf -> out
        k_gather32<<<gridNW, B, 0, stream>>>((const float4*)buf4, cnt, bucket, dinv, ovf_n, ovf, out4);
        // linear in-place
        k_linear4<<<1024, B, 0, stream>>>((const float4*)out4, W, b, out4);
    } else {
        const int gridF = (NN * D + B - 1) / B;
        const int gridEW = (NE * 64) / B;
        k_init_deg <<<gridN1, B, 0, stream>>>(dinv);
        k_count_deg<<<gridE1, B, 0, stream>>>(dst, dinv);
        k_dinv_f   <<<gridN1, B, 0, stream>>>(dinv);
        k_prop_init <<<gridF, B, 0, stream>>>(x, dinv, buf);
        k_prop_edges<<<gridEW, B, 0, stream>>>(x, src, dst, dinv, buf);
        k_prop_init <<<gridF, B, 0, stream>>>(buf, dinv, out);
        k_prop_edges<<<gridEW, B, 0, stream>>>(buf, src, dst, dinv, out);
        k_prop_init <<<gridF, B, 0, stream>>>(out, dinv, buf);
        k_prop_edges<<<gridEW, B, 0, stream>>>(out, src, dst, dinv, buf);
        k_linear<<<NN / 4, B, 0, stream>>>(buf, W, b, out);
    }
}

// Round 9
// 225.801 us; speedup vs baseline: 1.9210x; 1.0037x over previous
//
#include <hip/hip_runtime.h>

#define NN 100000
#define NE 1000000
#define D  64
#define CAP 32          // per-node bucket capacity; Poisson(10) ⇒ P(deg>32) ≈ 2e-9/node
#define OVF_CAP 16384
#define NCH_LIN 1563    // ceil(NN/64)

#define FILL_EPT 8                                        // edges per thread
#define FILL_CHUNK (256 * FILL_EPT)                       // 2048
#define FILL_NCHUNK ((NE + FILL_CHUNK - 1) / FILL_CHUNK)  // 489
#define PART_SZ 12500                                     // NN/8

// ======================= bucket build: XCD-partitioned writes =======================
// Block b: edge chunk b>>3, dst-partition b&7. The 8 sibling blocks share the
// chunk's lines via L2/IC; each bucket line is written from one XCD only
// (blockIdx%8 -> XCD round-robin), so partial lines merge once, not 8 times.
__global__ __launch_bounds__(256) void k_fill_bucket(const int* __restrict__ src,
                                                     const int* __restrict__ dst,
                                                     int* __restrict__ cnt,
                                                     int* __restrict__ bucket,
                                                     int* __restrict__ ovf_n,
                                                     int2* __restrict__ ovf) {
    const int part = blockIdx.x & 7;
    const int lo = part * PART_SZ, hi = lo + PART_SZ;
    const int base = (blockIdx.x >> 3) * FILL_CHUNK + threadIdx.x;
    #pragma unroll
    for (int it = 0; it < FILL_EPT; ++it) {
        int e = base + it * 256;
        if (e < NE) {
            int d = dst[e];
            if (d >= lo && d < hi) {
                int s = src[e];
                int c = atomicAdd(&cnt[d], 1);
                if (c < CAP) {
                    bucket[(size_t)d * CAP + c] = s;
                } else {                                 // ~never
                    int i = atomicAdd(ovf_n, 1);
                    if (i < OVF_CAP) ovf[i] = make_int2(s, d);
                }
            }
        }
    }
}

__global__ void k_dinv(const int* __restrict__ cnt, float* __restrict__ dinv) {
    int n = blockIdx.x * blockDim.x + threadIdx.x;
    if (n < NN) dinv[n] = rsqrtf((float)(cnt[n] + 1));   // +1 self loop
}

// ======================= propagation (pull, 4 nodes/wave, float4) =======================
// out[n] = dinv[n] * ( dinv[n]*in[n] + sum_{s in N(n)} dinv[s]*in[s] )
// Overflow edges (ovf_n ~always 0) handled inline: lanes scan the tiny list.

__global__ __launch_bounds__(256) void k_gather32(const float4* __restrict__ in4,
                                                  const int* __restrict__ cnt,
                                                  const int* __restrict__ bucket,
                                                  const float* __restrict__ dinv,
                                                  const int* __restrict__ ovf_n,
                                                  const int2* __restrict__ ovf,
                                                  float4* __restrict__ out4) {
    const int tid = threadIdx.x;
    const int l = tid & 15;
    const int n = blockIdx.x * 16 + (tid >> 4);   // 6250*16 == NN exactly

    const int deg = min(cnt[n], CAP);
    const float dn = dinv[n];

    float4 a0 = in4[(size_t)n * 16 + l];
    a0.x *= dn; a0.y *= dn; a0.z *= dn; a0.w *= dn;
    float4 a1 = make_float4(0.f, 0.f, 0.f, 0.f);
    float4 a2 = make_float4(0.f, 0.f, 0.f, 0.f);
    float4 a3 = make_float4(0.f, 0.f, 0.f, 0.f);

    if (deg > 0) {
        int   iA = (l < deg) ? l : 0;
        int   sA = bucket[n * CAP + iA];
        float wA = dinv[sA];
        const int kmax = deg < 16 ? deg : 16;
        int k = 0;
        for (; k + 3 < kmax; k += 4) {
            int   s0 = __shfl(sA, k + 0, 16);
            int   s1 = __shfl(sA, k + 1, 16);
            int   s2 = __shfl(sA, k + 2, 16);
            int   s3 = __shfl(sA, k + 3, 16);
            float w0 = __shfl(wA, k + 0, 16);
            float w1 = __shfl(wA, k + 1, 16);
            float w2 = __shfl(wA, k + 2, 16);
            float w3 = __shfl(wA, k + 3, 16);
            float4 r0 = in4[(size_t)s0 * 16 + l];
            float4 r1 = in4[(size_t)s1 * 16 + l];
            float4 r2 = in4[(size_t)s2 * 16 + l];
            float4 r3 = in4[(size_t)s3 * 16 + l];
            a0.x = fmaf(w0, r0.x, a0.x); a0.y = fmaf(w0, r0.y, a0.y);
            a0.z = fmaf(w0, r0.z, a0.z); a0.w = fmaf(w0, r0.w, a0.w);
            a1.x = fmaf(w1, r1.x, a1.x); a1.y = fmaf(w1, r1.y, a1.y);
            a1.z = fmaf(w1, r1.z, a1.z); a1.w = fmaf(w1, r1.w, a1.w);
            a2.x = fmaf(w2, r2.x, a2.x); a2.y = fmaf(w2, r2.y, a2.y);
            a2.z = fmaf(w2, r2.z, a2.z); a2.w = fmaf(w2, r2.w, a2.w);
            a3.x = fmaf(w3, r3.x, a3.x); a3.y = fmaf(w3, r3.y, a3.y);
            a3.z = fmaf(w3, r3.z, a3.z); a3.w = fmaf(w3, r3.w, a3.w);
        }
        for (; k < kmax; ++k) {
            int   s0 = __shfl(sA, k, 16);
            float w0 = __shfl(wA, k, 16);
            float4 r0 = in4[(size_t)s0 * 16 + l];
            a0.x = fmaf(w0, r0.x, a0.x); a0.y = fmaf(w0, r0.y, a0.y);
            a0.z = fmaf(w0, r0.z, a0.z); a0.w = fmaf(w0, r0.w, a0.w);
        }
        if (deg > 16) {   // ~3% of nodes
            int   iB = (16 + l < deg) ? (16 + l) : 0;
            int   sB = bucket[n * CAP + iB];
            float wB = dinv[sB];
            const int k2max = deg - 16;
            int k2 = 0;
            for (; k2 + 1 < k2max; k2 += 2) {
                int   s0 = __shfl(sB, k2 + 0, 16);
                int   s1 = __shfl(sB, k2 + 1, 16);
                float w0 = __shfl(wB, k2 + 0, 16);
                float w1 = __shfl(wB, k2 + 1, 16);
                float4 r0 = in4[(size_t)s0 * 16 + l];
                float4 r1 = in4[(size_t)s1 * 16 + l];
                a1.x = fmaf(w0, r0.x, a1.x); a1.y = fmaf(w0, r0.y, a1.y);
                a1.z = fmaf(w0, r0.z, a1.z); a1.w = fmaf(w0, r0.w, a1.w);
                a2.x = fmaf(w1, r1.x, a2.x); a2.y = fmaf(w1, r1.y, a2.y);
                a2.z = fmaf(w1, r1.z, a2.z); a2.w = fmaf(w1, r1.w, a2.w);
            }
            if (k2 < k2max) {
                int   s0 = __shfl(sB, k2, 16);
                float w0 = __shfl(wB, k2, 16);
                float4 r0 = in4[(size_t)s0 * 16 + l];
                a3.x = fmaf(w0, r0.x, a3.x); a3.y = fmaf(w0, r0.y, a3.y);
                a3.z = fmaf(w0, r0.z, a3.z); a3.w = fmaf(w0, r0.w, a3.w);
            }
        }
    }

    // inline overflow fixup (ovf_n is ~always 0; one hot scalar load)
    int m = *ovf_n;
    if (m > 0) {
        if (m > OVF_CAP) m = OVF_CAP;
        for (int i = 0; i < m; ++i) {
            int2 p = ovf[i];
            if (p.y == n) {
                float w = dinv[p.x];
                float4 r = in4[(size_t)p.x * 16 + l];
                a0.x = fmaf(w, r.x, a0.x); a0.y = fmaf(w, r.y, a0.y);
                a0.z = fmaf(w, r.z, a0.z); a0.w = fmaf(w, r.w, a0.w);
            }
        }
    }

    float4 r;
    r.x = dn * ((a0.x + a1.x) + (a2.x + a3.x));
    r.y = dn * ((a0.y + a1.y) + (a2.y + a3.y));
    r.z = dn * ((a0.z + a1.z) + (a2.z + a3.z));
    r.w = dn * ((a0.w + a1.w) + (a2.w + a3.w));
    out4[(size_t)n * 16 + l] = r;
}

// ======================= linear (in-place safe: row-local) =======================
__global__ __launch_bounds__(256) void k_linear4(const float4* in4,
                                                 const float* __restrict__ W,
                                                 const float* __restrict__ bias,
                                                 float4* out4) {
    __shared__ float4 Wq[64 * 16];     // Wq[i*16+l] = {W[4l+c][i], c=0..3}
    __shared__ float rowbuf[64][68];

    const int tid = threadIdx.x;
    for (int m = tid; m < 64 * 16; m += 256) {
        int i = m >> 4, l = m & 15;
        float4 v;
        v.x = W[(4 * l + 0) * 64 + i];
        v.y = W[(4 * l + 1) * 64 + i];
        v.z = W[(4 * l + 2) * 64 + i];
        v.w = W[(4 * l + 3) * 64 + i];
        Wq[m] = v;
    }
    __syncthreads();

    const int g = tid >> 4;
    const int l = tid & 15;
    const float4 bv = *(const float4*)&bias[4 * l];

    for (int chunk = blockIdx.x; chunk < NCH_LIN; chunk += gridDim.x) {
        const int nb = chunk * 64 + 4 * g;
        const int n0 = nb, n1 = nb + 1, n2 = nb + 2, n3 = nb + 3;
        float4 r0 = in4[(size_t)(n0 < NN ? n0 : NN - 1) * 16 + l];
        float4 r1 = in4[(size_t)(n1 < NN ? n1 : NN - 1) * 16 + l];
        float4 r2 = in4[(size_t)(n2 < NN ? n2 : NN - 1) * 16 + l];
        float4 r3 = in4[(size_t)(n3 < NN ? n3 : NN - 1) * 16 + l];
        *(float4*)&rowbuf[4 * g + 0][4 * l] = r0;
        *(float4*)&rowbuf[4 * g + 1][4 * l] = r1;
        *(float4*)&rowbuf[4 * g + 2][4 * l] = r2;
        *(float4*)&rowbuf[4 * g + 3][4 * l] = r3;

        float4 y0 = bv, y1 = bv, y2 = bv, y3 = bv;
        #pragma unroll
        for (int kq = 0; kq < 16; ++kq) {
            float4 ri0 = *(const float4*)&rowbuf[4 * g + 0][4 * kq];
            float4 ri1 = *(const float4*)&rowbuf[4 * g + 1][4 * kq];
            float4 ri2 = *(const float4*)&rowbuf[4 * g + 2][4 * kq];
            float4 ri3 = *(const float4*)&rowbuf[4 * g + 3][4 * kq];
            float4 wq0 = Wq[(4 * kq + 0) * 16 + l];
            float4 wq1 = Wq[(4 * kq + 1) * 16 + l];
            float4 wq2 = Wq[(4 * kq + 2) * 16 + l];
            float4 wq3 = Wq[(4 * kq + 3) * 16 + l];
            y0.x = fmaf(ri0.x, wq0.x, y0.x); y0.y = fmaf(ri0.x, wq0.y, y0.y);
            y0.z = fmaf(ri0.x, wq0.z, y0.z); y0.w = fmaf(ri0.x, wq0.w, y0.w);
            y0.x = fmaf(ri0.y, wq1.x, y0.x); y0.y = fmaf(ri0.y, wq1.y, y0.y);
            y0.z = fmaf(ri0.y, wq1.z, y0.z); y0.w = fmaf(ri0.y, wq1.w, y0.w);
            y0.x = fmaf(ri0.z, wq2.x, y0.x); y0.y = fmaf(ri0.z, wq2.y, y0.y);
            y0.z = fmaf(ri0.z, wq2.z, y0.z); y0.w = fmaf(ri0.z, wq2.w, y0.w);
            y0.x = fmaf(ri0.w, wq3.x, y0.x); y0.y = fmaf(ri0.w, wq3.y, y0.y);
            y0.z = fmaf(ri0.w, wq3.z, y0.z); y0.w = fmaf(ri0.w, wq3.w, y0.w);

            y1.x = fmaf(ri1.x, wq0.x, y1.x); y1.y = fmaf(ri1.x, wq0.y, y1.y);
            y1.z = fmaf(ri1.x, wq0.z, y1.z); y1.w = fmaf(ri1.x, wq0.w, y1.w);
            y1.x = fmaf(ri1.y, wq1.x, y1.x); y1.y = fmaf(ri1.y, wq1.y, y1.y);
            y1.z = fmaf(ri1.y, wq1.z, y1.z); y1.w = fmaf(ri1.y, wq1.w, y1.w);
            y1.x = fmaf(ri1.z, wq2.x, y1.x); y1.y = fmaf(ri1.z, wq2.y, y1.y);
            y1.z = fmaf(ri1.z, wq2.z, y1.z); y1.w = fmaf(ri1.z, wq2.w, y1.w);
            y1.x = fmaf(ri1.w, wq3.x, y1.x); y1.y = fmaf(ri1.w, wq3.y, y1.y);
            y1.z = fmaf(ri1.w, wq3.z, y1.z); y1.w = fmaf(ri1.w, wq3.w, y1.w);

            y2.x = fmaf(ri2.x, wq0.x, y2.x); y2.y = fmaf(ri2.x, wq0.y, y2.y);
            y2.z = fmaf(ri2.x, wq0.z, y2.z); y2.w = fmaf(ri2.x, wq0.w, y2.w);
            y2.x = fmaf(ri2.y, wq1.x, y2.x); y2.y = fmaf(ri2.y, wq1.y, y2.y);
            y2.z = fmaf(ri2.y, wq1.z, y2.z); y2.w = fmaf(ri2.y, wq1.w, y2.w);
            y2.x = fmaf(ri2.z, wq2.x, y2.x); y2.y = fmaf(ri2.z, wq2.y, y2.y);
            y2.z = fmaf(ri2.z, wq2.z, y2.z); y2.w = fmaf(ri2.z, wq2.w, y2.w);
            y2.x = fmaf(ri2.w, wq3.x, y2.x); y2.y = fmaf(ri2.w, wq3.y, y2.y);
            y2.z = fmaf(ri2.w, wq3.z, y2.z); y2.w = fmaf(ri2.w, wq3.w, y2.w);

            y3.x = fmaf(ri3.x, wq0.x, y3.x); y3.y = fmaf(ri3.x, wq0.y, y3.y);
            y3.z = fmaf(ri3.x, wq0.z, y3.z); y3.w = fmaf(ri3.x, wq0.w, y3.w);
            y3.x = fmaf(ri3.y, wq1.x, y3.x); y3.y = fmaf(ri3.y, wq1.y, y3.y);
            y3.z = fmaf(ri3.y, wq1.z, y3.z); y3.w = fmaf(ri3.y, wq1.w, y3.w);
            y3.x = fmaf(ri3.z, wq2.x, y3.x); y3.y = fmaf(ri3.z, wq2.y, y3.y);
            y3.z = fmaf(ri3.z, wq2.z, y3.z); y3.w = fmaf(ri3.z, wq2.w, y3.w);
            y3.x = fmaf(ri3.w, wq3.x, y3.x); y3.y = fmaf(ri3.w, wq3.y, y3.y);
            y3.z = fmaf(ri3.w, wq3.z, y3.z); y3.w = fmaf(ri3.w, wq3.w, y3.w);
        }
        if (n0 < NN) out4[(size_t)n0 * 16 + l] = y0;
        if (n1 < NN) out4[(size_t)n1 * 16 + l] = y1;
        if (n2 < NN) out4[(size_t)n2 * 16 + l] = y2;
        if (n3 < NN) out4[(size_t)n3 * 16 + l] = y3;
    }
}

// ======================= fallback path (atomic scatter, round-1) =======================

__global__ void k_init_deg(float* __restrict__ deg) {
    int n = blockIdx.x * blockDim.x + threadIdx.x;
    if (n < NN) deg[n] = 1.0f;
}
__global__ void k_count_deg(const int* __restrict__ dst, float* __restrict__ deg) {
    int e = blockIdx.x * blockDim.x + threadIdx.x;
    if (e < NE) atomicAdd(&deg[dst[e]], 1.0f);
}
__global__ void k_dinv_f(float* __restrict__ deg) {
    int n = blockIdx.x * blockDim.x + threadIdx.x;
    if (n < NN) deg[n] = rsqrtf(deg[n]);
}
__global__ void k_prop_init(const float* __restrict__ in, const float* __restrict__ dinv,
                            float* __restrict__ out) {
    int i = blockIdx.x * blockDim.x + threadIdx.x;
    if (i < NN * D) {
        int n = i >> 6;
        float di = dinv[n];
        out[i] = di * di * in[i];
    }
}
__global__ __launch_bounds__(256) void k_prop_edges(const float* __restrict__ in,
                                                    const int* __restrict__ src,
                                                    const int* __restrict__ dst,
                                                    const float* __restrict__ dinv,
                                                    float* __restrict__ out) {
    int t = blockIdx.x * blockDim.x + threadIdx.x;
    int e = t >> 6, f = t & 63;
    if (e < NE) {
        int s = src[e], d = dst[e];
        float w = dinv[s] * dinv[d];
        atomicAdd(&out[d * D + f], w * in[s * D + f]);
    }
}
__global__ __launch_bounds__(256) void k_linear(const float* __restrict__ in,
                                                const float* __restrict__ W,
                                                const float* __restrict__ bias,
                                                float* __restrict__ out) {
    __shared__ float Wt[64 * 65];
    __shared__ float rows[4][64];
    const int tid = threadIdx.x;
    for (int m = tid; m < 64 * 64; m += 256) {
        int o = m >> 6, i = m & 63;
        Wt[i * 65 + o] = W[m];
    }
    __syncthreads();
    const int wave = tid >> 6, lane = tid & 63;
    const float bo = bias[lane];
    for (int base = blockIdx.x * 4; base < NN; base += gridDim.x * 4) {
        int n = base + wave;
        if (n < NN) {
            rows[wave][lane] = in[n * D + lane];
            float acc = bo;
            #pragma unroll
            for (int i = 0; i < 64; ++i)
                acc = fmaf(rows[wave][i], Wt[i * 65 + lane], acc);
            out[n * D + lane] = acc;
        }
    }
}

// ======================= launch =======================

extern "C" void kernel_launch(void* const* d_in, const int* in_sizes, int n_in,
                              void* d_out, int out_size, void* d_ws, size_t ws_size,
                              hipStream_t stream) {
    const float* x   = (const float*)d_in[0];
    const int*   ei  = (const int*)d_in[1];
    const float* W   = (const float*)d_in[2];
    const float* b   = (const float*)d_in[3];
    float* out = (float*)d_out;

    const int* src = ei;        // edge_index[0]
    const int* dst = ei + NE;   // edge_index[1]

    char* ws = (char*)d_ws;
    size_t off = 0;
    auto take = [&](size_t bytes) -> char* {
        char* p = ws + off;
        off = (off + bytes + 255) & ~(size_t)255;
        return p;
    };

    int*   cnt    = (int*)take((size_t)NN * 4);
    float* dinv   = (float*)take((size_t)NN * 4);
    int*   ovf_n  = (int*)take(256);
    int2*  ovf    = (int2*)take((size_t)OVF_CAP * 8);
    float* buf    = (float*)take((size_t)NN * D * 4);
    int*   bucket = (int*)take((size_t)NN * CAP * 4);
    const bool use_bucket = (off <= ws_size);

    const int B = 256;
    const int gridE1 = (NE + B - 1) / B;   // 3907
    const int gridN1 = (NN + B - 1) / B;   // 391
    const int gridNW = NN / 16;            // 6250

    if (use_bucket) {
        hipMemsetAsync(cnt, 0, (size_t)NN * 4, stream);
        hipMemsetAsync(ovf_n, 0, 4, stream);
        k_fill_bucket<<<FILL_NCHUNK * 8, B, 0, stream>>>(src, dst, cnt, bucket, ovf_n, ovf);
        k_dinv<<<gridN1, B, 0, stream>>>(cnt, dinv);

        const float4* x4   = (const float4*)x;
        float4*       out4 = (float4*)out;
        float4*       buf4 = (float4*)buf;
        // hop1: x -> out
        k_gather32<<<gridNW, B, 0, stream>>>(x4, cnt, bucket, dinv, ovf_n, ovf, out4);
        // hop2: out -> buf
        k_gather32<<<gridNW, B, 0, stream>>>((const float4*)out4, cnt, bucket, dinv, ovf_n, ovf, buf4);
        // hop3: buf -> out
        k_gather32<<<gridNW, B, 0, stream>>>((const float4*)buf4, cnt, bucket, dinv, ovf_n, ovf, out4);
        // linear in-place
        k_linear4<<<1024, B, 0, stream>>>((const float4*)out4, W, b, out4);
    } else {
        const int gridF = (NN * D + B - 1) / B;
        const int gridEW = (NE * 64) / B;
        k_init_deg <<<gridN1, B, 0, stream>>>(dinv);
        k_count_deg<<<gridE1, B, 0, stream>>>(dst, dinv);
        k_dinv_f   <<<gridN1, B, 0, stream>>>(dinv);
        k_prop_init <<<gridF, B, 0, stream>>>(x, dinv, buf);
        k_prop_edges<<<gridEW, B, 0, stream>>>(x, src, dst, dinv, buf);
        k_prop_init <<<gridF, B, 0, stream>>>(buf, dinv, out);
        k_prop_edges<<<gridEW, B, 0, stream>>>(buf, src, dst, dinv, out);
        k_prop_init <<<gridF, B, 0, stream>>>(out, dinv, buf);
        k_prop_edges<<<gridEW, B, 0, stream>>>(out, src, dst, dinv, buf);
        k_linear<<<NN / 4, B, 0, stream>>>(buf, W, b, out);
    }
}

// Round 10
// 172.980 us; speedup vs baseline: 2.5076x; 1.3054x over previous
//
#include <hip/hip_runtime.h>

#define NN 100000
#define NE 1000000
#define D  64
#define CAP 32          // per-node bucket capacity; Poisson(10) ⇒ P(deg>32) ≈ 2e-9/node
#define OVF_CAP 16384

#define FILL_EPT 8                                        // edges per thread
#define FILL_CHUNK (256 * FILL_EPT)                       // 2048
#define FILL_NCHUNK ((NE + FILL_CHUNK - 1) / FILL_CHUNK)  // 489
#define PART_SZ 12500                                     // NN/8

// ======================= bf16 helpers (RNE pack, shift unpack) =======================
__device__ __forceinline__ unsigned bf16rne(float f) {
    unsigned h = __float_as_uint(f);
    return (h + 0x7fffu + ((h >> 16) & 1u)) >> 16;
}
__device__ __forceinline__ uint2 pack4(float4 v) {
    uint2 o;
    o.x = bf16rne(v.x) | (bf16rne(v.y) << 16);
    o.y = bf16rne(v.z) | (bf16rne(v.w) << 16);
    return o;
}
__device__ __forceinline__ float4 unpack4(uint2 u) {
    float4 f;
    f.x = __uint_as_float(u.x << 16);
    f.y = __uint_as_float(u.x & 0xffff0000u);
    f.z = __uint_as_float(u.y << 16);
    f.w = __uint_as_float(u.y & 0xffff0000u);
    return f;
}

// ======================= bucket build: XCD-partitioned writes =======================
__global__ __launch_bounds__(256) void k_fill_bucket(const int* __restrict__ src,
                                                     const int* __restrict__ dst,
                                                     int* __restrict__ cnt,
                                                     int* __restrict__ bucket,
                                                     int* __restrict__ ovf_n,
                                                     int2* __restrict__ ovf) {
    const int part = blockIdx.x & 7;
    const int lo = part * PART_SZ, hi = lo + PART_SZ;
    const int base = (blockIdx.x >> 3) * FILL_CHUNK + threadIdx.x;
    #pragma unroll
    for (int it = 0; it < FILL_EPT; ++it) {
        int e = base + it * 256;
        if (e < NE) {
            int d = dst[e];
            if (d >= lo && d < hi) {
                int s = src[e];
                int c = atomicAdd(&cnt[d], 1);
                if (c < CAP) {
                    bucket[(size_t)d * CAP + c] = s;
                } else {                                 // ~never
                    int i = atomicAdd(ovf_n, 1);
                    if (i < OVF_CAP) ovf[i] = make_int2(s, d);
                }
            }
        }
    }
}

__global__ void k_dinv(const int* __restrict__ cnt, float* __restrict__ dinv) {
    int n = blockIdx.x * blockDim.x + threadIdx.x;
    if (n < NN) dinv[n] = rsqrtf((float)(cnt[n] + 1));   // +1 self loop
}

// ======================= fp32 -> bf16 convert (x -> P) =======================
// grid 12500*256 == NN*32 exactly
__global__ void k_cvt(const float2* __restrict__ x2, unsigned* __restrict__ xb) {
    int i = blockIdx.x * blockDim.x + threadIdx.x;
    float2 v = x2[i];
    xb[i] = bf16rne(v.x) | (bf16rne(v.y) << 16);
}

// ======================= propagation (pull, bf16 rows, fp32 accum) =======================
// out[n] = dinv[n] * ( dinv[n]*in[n] + sum_{s in N(n)} dinv[s]*in[s] )

__global__ __launch_bounds__(256) void k_gather_bf16(const uint2* __restrict__ in2,
                                                     const int* __restrict__ cnt,
                                                     const int* __restrict__ bucket,
                                                     const float* __restrict__ dinv,
                                                     const int* __restrict__ ovf_n,
                                                     const int2* __restrict__ ovf,
                                                     uint2* __restrict__ out2) {
    const int tid = threadIdx.x;
    const int l = tid & 15;
    const int n = blockIdx.x * 16 + (tid >> 4);   // 6250*16 == NN exactly

    const int deg = min(cnt[n], CAP);
    const float dn = dinv[n];

    float4 a0 = unpack4(in2[(size_t)n * 16 + l]);
    a0.x *= dn; a0.y *= dn; a0.z *= dn; a0.w *= dn;
    float4 a1 = make_float4(0.f, 0.f, 0.f, 0.f);
    float4 a2 = make_float4(0.f, 0.f, 0.f, 0.f);
    float4 a3 = make_float4(0.f, 0.f, 0.f, 0.f);

    if (deg > 0) {
        int   iA = (l < deg) ? l : 0;
        int   sA = bucket[(size_t)n * CAP + iA];
        float wA = dinv[sA];
        const int kmax = deg < 16 ? deg : 16;
        int k = 0;
        for (; k + 3 < kmax; k += 4) {
            int   s0 = __shfl(sA, k + 0, 16);
            int   s1 = __shfl(sA, k + 1, 16);
            int   s2 = __shfl(sA, k + 2, 16);
            int   s3 = __shfl(sA, k + 3, 16);
            float w0 = __shfl(wA, k + 0, 16);
            float w1 = __shfl(wA, k + 1, 16);
            float w2 = __shfl(wA, k + 2, 16);
            float w3 = __shfl(wA, k + 3, 16);
            float4 r0 = unpack4(in2[(size_t)s0 * 16 + l]);
            float4 r1 = unpack4(in2[(size_t)s1 * 16 + l]);
            float4 r2 = unpack4(in2[(size_t)s2 * 16 + l]);
            float4 r3 = unpack4(in2[(size_t)s3 * 16 + l]);
            a0.x = fmaf(w0, r0.x, a0.x); a0.y = fmaf(w0, r0.y, a0.y);
            a0.z = fmaf(w0, r0.z, a0.z); a0.w = fmaf(w0, r0.w, a0.w);
            a1.x = fmaf(w1, r1.x, a1.x); a1.y = fmaf(w1, r1.y, a1.y);
            a1.z = fmaf(w1, r1.z, a1.z); a1.w = fmaf(w1, r1.w, a1.w);
            a2.x = fmaf(w2, r2.x, a2.x); a2.y = fmaf(w2, r2.y, a2.y);
            a2.z = fmaf(w2, r2.z, a2.z); a2.w = fmaf(w2, r2.w, a2.w);
            a3.x = fmaf(w3, r3.x, a3.x); a3.y = fmaf(w3, r3.y, a3.y);
            a3.z = fmaf(w3, r3.z, a3.z); a3.w = fmaf(w3, r3.w, a3.w);
        }
        for (; k < kmax; ++k) {
            int   s0 = __shfl(sA, k, 16);
            float w0 = __shfl(wA, k, 16);
            float4 r0 = unpack4(in2[(size_t)s0 * 16 + l]);
            a0.x = fmaf(w0, r0.x, a0.x); a0.y = fmaf(w0, r0.y, a0.y);
            a0.z = fmaf(w0, r0.z, a0.z); a0.w = fmaf(w0, r0.w, a0.w);
        }
        if (deg > 16) {   // ~3% of nodes
            int   iB = (16 + l < deg) ? (16 + l) : 0;
            int   sB = bucket[(size_t)n * CAP + iB];
            float wB = dinv[sB];
            const int k2max = deg - 16;
            int k2 = 0;
            for (; k2 + 1 < k2max; k2 += 2) {
                int   s0 = __shfl(sB, k2 + 0, 16);
                int   s1 = __shfl(sB, k2 + 1, 16);
                float w0 = __shfl(wB, k2 + 0, 16);
                float w1 = __shfl(wB, k2 + 1, 16);
                float4 r0 = unpack4(in2[(size_t)s0 * 16 + l]);
                float4 r1 = unpack4(in2[(size_t)s1 * 16 + l]);
                a1.x = fmaf(w0, r0.x, a1.x); a1.y = fmaf(w0, r0.y, a1.y);
                a1.z = fmaf(w0, r0.z, a1.z); a1.w = fmaf(w0, r0.w, a1.w);
                a2.x = fmaf(w1, r1.x, a2.x); a2.y = fmaf(w1, r1.y, a2.y);
                a2.z = fmaf(w1, r1.z, a2.z); a2.w = fmaf(w1, r1.w, a2.w);
            }
            if (k2 < k2max) {
                int   s0 = __shfl(sB, k2, 16);
                float w0 = __shfl(wB, k2, 16);
                float4 r0 = unpack4(in2[(size_t)s0 * 16 + l]);
                a3.x = fmaf(w0, r0.x, a3.x); a3.y = fmaf(w0, r0.y, a3.y);
                a3.z = fmaf(w0, r0.z, a3.z); a3.w = fmaf(w0, r0.w, a3.w);
            }
        }
    }

    // inline overflow fixup (ovf_n is ~always 0; one hot scalar load)
    int m = *ovf_n;
    if (m > 0) {
        if (m > OVF_CAP) m = OVF_CAP;
        for (int i = 0; i < m; ++i) {
            int2 p = ovf[i];
            if (p.y == n) {
                float w = dinv[p.x];
                float4 r = unpack4(in2[(size_t)p.x * 16 + l]);
                a0.x = fmaf(w, r.x, a0.x); a0.y = fmaf(w, r.y, a0.y);
                a0.z = fmaf(w, r.z, a0.z); a0.w = fmaf(w, r.w, a0.w);
            }
        }
    }

    float4 r;
    r.x = dn * ((a0.x + a1.x) + (a2.x + a3.x));
    r.y = dn * ((a0.y + a1.y) + (a2.y + a3.y));
    r.z = dn * ((a0.z + a1.z) + (a2.z + a3.z));
    r.w = dn * ((a0.w + a1.w) + (a2.w + a3.w));
    out2[(size_t)n * 16 + l] = pack4(r);
}

// ======================= linear: W in registers, readlane row broadcast =======================
// wave = node, lane = output column. W[lane][0..63] lives in 64 VGPRs (constant-
// indexed after full unroll). Row broadcast via v_readlane (VALU pipe, no LDS).
__global__ __launch_bounds__(256) void k_linear_reg(const unsigned short* __restrict__ inb,
                                                    const float* __restrict__ W,
                                                    const float* __restrict__ bias,
                                                    float* __restrict__ out) {
    const int lane = threadIdx.x & 63;
    const int wid  = (blockIdx.x * blockDim.x + threadIdx.x) >> 6;
    const int nw   = (gridDim.x * blockDim.x) >> 6;

    float w[64];
    const float4* W4 = (const float4*)W;
    #pragma unroll
    for (int i = 0; i < 16; ++i) {
        float4 q = W4[lane * 16 + i];
        w[4 * i + 0] = q.x; w[4 * i + 1] = q.y;
        w[4 * i + 2] = q.z; w[4 * i + 3] = q.w;
    }
    const float bo = bias[lane];

    for (int n = wid; n < NN; n += nw) {
        float rl = __uint_as_float((unsigned)inb[(size_t)n * 64 + lane] << 16);
        int rli = __float_as_int(rl);
        float y0 = bo, y1 = 0.f;
        #pragma unroll
        for (int i = 0; i < 64; i += 2) {
            y0 = fmaf(__int_as_float(__builtin_amdgcn_readlane(rli, i)),     w[i],     y0);
            y1 = fmaf(__int_as_float(__builtin_amdgcn_readlane(rli, i + 1)), w[i + 1], y1);
        }
        out[(size_t)n * 64 + lane] = y0 + y1;
    }
}

// ======================= fallback path (atomic scatter, fp32) =======================

__global__ void k_init_deg(float* __restrict__ deg) {
    int n = blockIdx.x * blockDim.x + threadIdx.x;
    if (n < NN) deg[n] = 1.0f;
}
__global__ void k_count_deg(const int* __restrict__ dst, float* __restrict__ deg) {
    int e = blockIdx.x * blockDim.x + threadIdx.x;
    if (e < NE) atomicAdd(&deg[dst[e]], 1.0f);
}
__global__ void k_dinv_f(float* __restrict__ deg) {
    int n = blockIdx.x * blockDim.x + threadIdx.x;
    if (n < NN) deg[n] = rsqrtf(deg[n]);
}
__global__ void k_prop_init(const float* __restrict__ in, const float* __restrict__ dinv,
                            float* __restrict__ out) {
    int i = blockIdx.x * blockDim.x + threadIdx.x;
    if (i < NN * D) {
        int n = i >> 6;
        float di = dinv[n];
        out[i] = di * di * in[i];
    }
}
__global__ __launch_bounds__(256) void k_prop_edges(const float* __restrict__ in,
                                                    const int* __restrict__ src,
                                                    const int* __restrict__ dst,
                                                    const float* __restrict__ dinv,
                                                    float* __restrict__ out) {
    int t = blockIdx.x * blockDim.x + threadIdx.x;
    int e = t >> 6, f = t & 63;
    if (e < NE) {
        int s = src[e], d = dst[e];
        float w = dinv[s] * dinv[d];
        atomicAdd(&out[d * D + f], w * in[s * D + f]);
    }
}
__global__ __launch_bounds__(256) void k_linear(const float* __restrict__ in,
                                                const float* __restrict__ W,
                                                const float* __restrict__ bias,
                                                float* __restrict__ out) {
    __shared__ float Wt[64 * 65];
    __shared__ float rows[4][64];
    const int tid = threadIdx.x;
    for (int m = tid; m < 64 * 64; m += 256) {
        int o = m >> 6, i = m & 63;
        Wt[i * 65 + o] = W[m];
    }
    __syncthreads();
    const int wave = tid >> 6, lane = tid & 63;
    const float bo = bias[lane];
    for (int base = blockIdx.x * 4; base < NN; base += gridDim.x * 4) {
        int n = base + wave;
        if (n < NN) {
            rows[wave][lane] = in[n * D + lane];
            float acc = bo;
            #pragma unroll
            for (int i = 0; i < 64; ++i)
                acc = fmaf(rows[wave][i], Wt[i * 65 + lane], acc);
            out[n * D + lane] = acc;
        }
    }
}

// ======================= launch =======================

extern "C" void kernel_launch(void* const* d_in, const int* in_sizes, int n_in,
                              void* d_out, int out_size, void* d_ws, size_t ws_size,
                              hipStream_t stream) {
    const float* x   = (const float*)d_in[0];
    const int*   ei  = (const int*)d_in[1];
    const float* W   = (const float*)d_in[2];
    const float* b   = (const float*)d_in[3];
    float* out = (float*)d_out;

    const int* src = ei;        // edge_index[0]
    const int* dst = ei + NE;   // edge_index[1]

    char* ws = (char*)d_ws;
    size_t off = 0;
    auto take = [&](size_t bytes) -> char* {
        char* p = ws + off;
        off = (off + bytes + 255) & ~(size_t)255;
        return p;
    };

    int*      cnt    = (int*)take((size_t)NN * 4);
    float*    dinv   = (float*)take((size_t)NN * 4);
    int*      ovf_n  = (int*)take(256);
    int2*     ovf    = (int2*)take((size_t)OVF_CAP * 8);
    unsigned* P      = (unsigned*)take((size_t)NN * 32 * 4);   // bf16 buffer (12.8 MB)
    unsigned* Q      = (unsigned*)take((size_t)NN * 32 * 4);   // bf16 buffer (12.8 MB)
    int*      bucket = (int*)take((size_t)NN * CAP * 4);
    float*    buf    = (float*)P;   // fallback fp32 buffer: spans P+Q (25.6 MB, contiguous)
    const bool use_bucket = (off <= ws_size);

    const int B = 256;
    const int gridE1 = (NE + B - 1) / B;   // 3907
    const int gridN1 = (NN + B - 1) / B;   // 391
    const int gridNW = NN / 16;            // 6250

    if (use_bucket) {
        hipMemsetAsync(cnt, 0, (size_t)NN * 4, stream);
        hipMemsetAsync(ovf_n, 0, 4, stream);
        k_fill_bucket<<<FILL_NCHUNK * 8, B, 0, stream>>>(src, dst, cnt, bucket, ovf_n, ovf);
        k_dinv<<<gridN1, B, 0, stream>>>(cnt, dinv);
        k_cvt<<<12500, B, 0, stream>>>((const float2*)x, P);   // x -> P (bf16)

        // hop1: P -> Q
        k_gather_bf16<<<gridNW, B, 0, stream>>>((const uint2*)P, cnt, bucket, dinv, ovf_n, ovf, (uint2*)Q);
        // hop2: Q -> P
        k_gather_bf16<<<gridNW, B, 0, stream>>>((const uint2*)Q, cnt, bucket, dinv, ovf_n, ovf, (uint2*)P);
        // hop3: P -> Q
        k_gather_bf16<<<gridNW, B, 0, stream>>>((const uint2*)P, cnt, bucket, dinv, ovf_n, ovf, (uint2*)Q);
        // linear: Q -> out (fp32 W, fp32 accum)
        k_linear_reg<<<1024, B, 0, stream>>>((const unsigned short*)Q, W, b, out);
    } else {
        const int gridF = (NN * D + B - 1) / B;
        const int gridEW = (NE * 64) / B;
        k_init_deg <<<gridN1, B, 0, stream>>>(dinv);
        k_count_deg<<<gridE1, B, 0, stream>>>(dst, dinv);
        k_dinv_f   <<<gridN1, B, 0, stream>>>(dinv);
        k_prop_init <<<gridF, B, 0, stream>>>(x, dinv, buf);
        k_prop_edges<<<gridEW, B, 0, stream>>>(x, src, dst, dinv, buf);
        k_prop_init <<<gridF, B, 0, stream>>>(buf, dinv, out);
        k_prop_edges<<<gridEW, B, 0, stream>>>(buf, src, dst, dinv, out);
        k_prop_init <<<gridF, B, 0, stream>>>(out, dinv, buf);
        k_prop_edges<<<gridEW, B, 0, stream>>>(out, src, dst, dinv, buf);
        k_linear<<<NN / 4, B, 0, stream>>>(buf, W, b, out);
    }
}